// Round 1
// baseline (526.498 us; speedup 1.0000x reference)
//
#include <hip/hip_runtime.h>
#include <hip/hip_bf16.h>
#include <stdint.h>

// ---------------------------------------------------------------------------
// Attention layer: x->QKV proj -> RoPE -> causal GQA flash attn -> O proj
// B=2 S=2048 D=2048 H=32 KVH=8 HD=64. All GEMMs bf16 MFMA 16x16x32, fp32 accum.
// ---------------------------------------------------------------------------

#define NEG_BIG (-1e9f)

typedef __bf16 bf16x8 __attribute__((ext_vector_type(8)));
typedef float f32x4 __attribute__((ext_vector_type(4)));

__device__ inline uint16_t f2bf(float x) {
    __hip_bfloat16 h = __float2bfloat16(x);
    return __builtin_bit_cast(uint16_t, h);
}
__device__ inline float bf2f(uint16_t u) {
    uint32_t t = (uint32_t)u << 16;
    return __builtin_bit_cast(float, t);
}

__device__ inline void async_cp16(const void* g, void* l) {
    __builtin_amdgcn_global_load_lds(
        (const __attribute__((address_space(1))) uint32_t*)g,
        (__attribute__((address_space(3))) uint32_t*)l,
        16 /*bytes*/, 0 /*offset*/, 0 /*aux*/);
}

// ------------------------- fp32 -> bf16 cast (4/thread) ---------------------
__global__ void cvt4(const float* __restrict__ in, uint16_t* __restrict__ out, int n4) {
    int i = blockIdx.x * blockDim.x + threadIdx.x;
    if (i >= n4) return;
    const float4 v = ((const float4*)in)[i];
    ushort4 o;
    o.x = f2bf(v.x); o.y = f2bf(v.y); o.z = f2bf(v.z); o.w = f2bf(v.w);
    ((ushort4*)out)[i] = o;
}

// ------------------- build concat W = [wq; wk; wv] in bf16 ------------------
// out[n][k], n in [0,3072): n<2048 -> wq row n; n<2560 -> wk row n-2048; else wv
__global__ void build_wqkv(const float* __restrict__ wq, const float* __restrict__ wk,
                           const float* __restrict__ wv, uint16_t* __restrict__ out) {
    int i = blockIdx.x * blockDim.x + threadIdx.x;   // one per 4 elements
    if (i >= (3072 * 2048) / 4) return;
    int e = i * 4;
    int row = e >> 11;           // /2048
    int col = e & 2047;
    const float* src = (row < 2048) ? (wq + (long)row * 2048 + col)
                     : (row < 2560) ? (wk + (long)(row - 2048) * 2048 + col)
                                    : (wv + (long)(row - 2560) * 2048 + col);
    const float4 v = *(const float4*)src;
    ushort4 o;
    o.x = f2bf(v.x); o.y = f2bf(v.y); o.z = f2bf(v.z); o.w = f2bf(v.w);
    ((ushort4*)(out + e))[0] = o;
}

// ------------------------------- GEMM (NT) ----------------------------------
// C[m][n] = sum_k A[m][k] * B[n][k];  A:[M][K] bf16, B:[N][K] bf16.
// 128x128 tile, BK=32, 256 threads (4 waves, 2x2), global_load_lds staging.
template <int OUT_BF16>
__global__ __launch_bounds__(256) void gemm_bt(const uint16_t* __restrict__ A,
                                               const uint16_t* __restrict__ Bw,
                                               void* __restrict__ Cout,
                                               int M, int N, int K) {
    __shared__ __align__(16) uint16_t Asm[128 * 32];
    __shared__ __align__(16) uint16_t Bsm[128 * 32];
    const int t = threadIdx.x;
    const int l = t & 63;
    const int w = t >> 6;
    const int wr = w >> 1, wc = w & 1;
    const int c = l & 15, g = l >> 4;
    const long row0 = (long)blockIdx.x * 128;
    const long col0 = (long)blockIdx.y * 128;

    f32x4 acc[4][4] = {};

    const uint16_t* aSrc = A + (row0 + (t >> 2)) * (long)K + (t & 3) * 8;
    const uint16_t* bSrc = Bw + (col0 + (t >> 2)) * (long)K + (t & 3) * 8;
    const long half = 64L * K;

    for (int k0 = 0; k0 < K; k0 += 32) {
        __syncthreads();                       // previous-iter LDS reads done
        async_cp16(aSrc + k0, &Asm[t * 8]);
        async_cp16(aSrc + half + k0, &Asm[2048 + t * 8]);
        async_cp16(bSrc + k0, &Bsm[t * 8]);
        async_cp16(bSrc + half + k0, &Bsm[2048 + t * 8]);
        __syncthreads();                       // staging complete (vmcnt drained)

        bf16x8 aF[4], bF[4];
        const int ko = g * 8;
#pragma unroll
        for (int m = 0; m < 4; ++m)
            aF[m] = *(const bf16x8*)&Asm[(wr * 64 + m * 16 + c) * 32 + ko];
#pragma unroll
        for (int n = 0; n < 4; ++n)
            bF[n] = *(const bf16x8*)&Bsm[(wc * 64 + n * 16 + c) * 32 + ko];
#pragma unroll
        for (int m = 0; m < 4; ++m)
#pragma unroll
            for (int n = 0; n < 4; ++n)
                acc[m][n] = __builtin_amdgcn_mfma_f32_16x16x32_bf16(aF[m], bF[n], acc[m][n], 0, 0, 0);
    }

#pragma unroll
    for (int m = 0; m < 4; ++m) {
        const long rg = row0 + wr * 64 + m * 16 + g * 4;
#pragma unroll
        for (int n = 0; n < 4; ++n) {
            const long cg = col0 + wc * 64 + n * 16 + c;
#pragma unroll
            for (int r = 0; r < 4; ++r) {
                float v = acc[m][n][r];
                if (OUT_BF16)
                    ((uint16_t*)Cout)[(rg + r) * (long)N + cg] = f2bf(v);
                else
                    ((float*)Cout)[(rg + r) * (long)N + cg] = v;
            }
        }
    }
}

// ------------------------------ RoPE in-place -------------------------------
// qkv[m][col], m=b*2048+s, q cols [0,2048) heads of 64, k cols [2048,2560).
// pair j: q part j<1024 -> col=2*j ; k part -> col=2048+2*(j-1024); d2 = j&31
__global__ void rope_inplace(uint16_t* __restrict__ qkv,
                             const float* __restrict__ cosT,
                             const float* __restrict__ sinT) {
    const int PPR = 1280;  // pairs per row: 1024 q + 256 k
    int idx = blockIdx.x * blockDim.x + threadIdx.x;
    if (idx >= 4096 * PPR) return;
    int m = idx / PPR;
    int j = idx - m * PPR;
    int col = (j < 1024) ? (2 * j) : (2048 + 2 * (j - 1024));
    int s = m & 2047;
    int d2 = j & 31;
    float cc = cosT[s * 32 + d2];
    float ss = sinT[s * 32 + d2];
    uint32_t* p = (uint32_t*)(qkv + (long)m * 3072 + col);
    uint32_t v = *p;
    float re = bf2f((uint16_t)(v & 0xffffu));
    float im = bf2f((uint16_t)(v >> 16));
    float orr = re * cc - im * ss;
    float oi = re * ss + im * cc;
    *p = (uint32_t)f2bf(orr) | ((uint32_t)f2bf(oi) << 16);
}

// ---------------------------- flash attention -------------------------------
// block = (b, h, 64-row q tile); 4 waves x 16 q-rows; KV tiles of 32.
// qkv layout: row m=b*2048+s, cols: q: h*64+d ; k: 2048+kvh*64+d ; v: 2560+kvh*64+d
__global__ __launch_bounds__(256) void attn_fwd(const uint16_t* __restrict__ qkv,
                                                uint16_t* __restrict__ outb) {
    const int bid = blockIdx.x;
    const int qt = bid & 31;
    const int h = (bid >> 5) & 31;
    const int b = bid >> 10;
    const int kvh = h >> 2;
    const int t = threadIdx.x;
    const int l = t & 63, w = t >> 6;
    const int c = l & 15, g = l >> 4;
    const int q0 = qt * 64 + w * 16;    // this wave's first q row

    // Q fragments: lane holds Q[q0+c][g*8+j (+32)]
    const uint16_t* qp = qkv + ((long)(b * 2048 + q0 + c)) * 3072 + h * 64 + g * 8;
    const bf16x8 qf0 = *(const bf16x8*)qp;
    const bf16x8 qf1 = *(const bf16x8*)(qp + 32);

    float m_run[4], l_run[4];
    f32x4 accO[4] = {};
#pragma unroll
    for (int r = 0; r < 4; ++r) { m_run[r] = -1e30f; l_run[r] = 0.f; }

    __shared__ __align__(16) uint16_t Pbuf[4][16 * 32];

    const uint16_t* kbase = qkv + (long)b * 2048 * 3072 + 2048 + kvh * 64;
    const uint16_t* vbase = qkv + (long)b * 2048 * 3072 + 2560 + kvh * 64;
    const int ntiles = qt * 2 + 2;      // keys 0 .. qt*64+63

    for (int tile = 0; tile < ntiles; ++tile) {
        const int k0 = tile * 32;
        // S = Q K^T : two 16-key column groups, accumulate over d=0..63
        f32x4 s[2];
#pragma unroll
        for (int n = 0; n < 2; ++n) {
            const uint16_t* kp = kbase + (long)(k0 + n * 16 + c) * 3072 + g * 8;
            bf16x8 kf0 = *(const bf16x8*)kp;
            bf16x8 kf1 = *(const bf16x8*)(kp + 32);
            f32x4 z = {};
            z = __builtin_amdgcn_mfma_f32_16x16x32_bf16(qf0, kf0, z, 0, 0, 0);
            z = __builtin_amdgcn_mfma_f32_16x16x32_bf16(qf1, kf1, z, 0, 0, 0);
            s[n] = z;
        }
        // scale + causal mask;  D-layout: row(q)=4g+r, col(key)=c+16n
#pragma unroll
        for (int n = 0; n < 2; ++n) {
            const int key = k0 + n * 16 + c;
#pragma unroll
            for (int r = 0; r < 4; ++r) {
                const int qg = q0 + 4 * g + r;
                s[n][r] = s[n][r] * 0.125f + (key > qg ? NEG_BIG : 0.f);
            }
        }
        // online softmax (row-reduce across the 16 lanes of each group)
        float p0[4], p1[4], alpha[4];
#pragma unroll
        for (int r = 0; r < 4; ++r) {
            float v = fmaxf(s[0][r], s[1][r]);
            v = fmaxf(v, __shfl_xor(v, 1));
            v = fmaxf(v, __shfl_xor(v, 2));
            v = fmaxf(v, __shfl_xor(v, 4));
            v = fmaxf(v, __shfl_xor(v, 8));
            const float mnew = fmaxf(m_run[r], v);
            alpha[r] = __expf(m_run[r] - mnew);
            m_run[r] = mnew;
            p0[r] = __expf(s[0][r] - mnew);
            p1[r] = __expf(s[1][r] - mnew);
            float sm = p0[r] + p1[r];
            sm += __shfl_xor(sm, 1);
            sm += __shfl_xor(sm, 2);
            sm += __shfl_xor(sm, 4);
            sm += __shfl_xor(sm, 8);
            l_run[r] = l_run[r] * alpha[r] + sm;
        }
#pragma unroll
        for (int nn = 0; nn < 4; ++nn)
#pragma unroll
            for (int r = 0; r < 4; ++r)
                accO[nn][r] *= alpha[r];

        // P (C/D layout) -> LDS -> A-fragment layout
#pragma unroll
        for (int r = 0; r < 4; ++r) {
            Pbuf[w][(4 * g + r) * 32 + c] = f2bf(p0[r]);
            Pbuf[w][(4 * g + r) * 32 + 16 + c] = f2bf(p1[r]);
        }
        __syncthreads();   // uniform across block; orders LDS write->read
        const bf16x8 pf = *(const bf16x8*)&Pbuf[w][c * 32 + g * 8];

        // V fragments (column gather, L2-resident) + PV MFMA
#pragma unroll
        for (int nn = 0; nn < 4; ++nn) {
            const __bf16* vp = (const __bf16*)(vbase + (long)(k0 + g * 8) * 3072 + nn * 16 + c);
            bf16x8 vF;
#pragma unroll
            for (int j = 0; j < 8; ++j) vF[j] = vp[(long)j * 3072];
            accO[nn] = __builtin_amdgcn_mfma_f32_16x16x32_bf16(pf, vF, accO[nn], 0, 0, 0);
        }
    }

    // epilogue: out[b, q, h*64 + d] = accO / l
#pragma unroll
    for (int nn = 0; nn < 4; ++nn) {
#pragma unroll
        for (int r = 0; r < 4; ++r) {
            const int qg = q0 + 4 * g + r;
            const float o = accO[nn][r] / l_run[r];
            outb[(long)(b * 2048 + qg) * 2048 + h * 64 + nn * 16 + c] = f2bf(o);
        }
    }
}

// ---------------------------------------------------------------------------
extern "C" void kernel_launch(void* const* d_in, const int* in_sizes, int n_in,
                              void* d_out, int out_size, void* d_ws, size_t ws_size,
                              hipStream_t stream) {
    const float* x    = (const float*)d_in[0];
    const float* wq   = (const float*)d_in[1];
    const float* wk   = (const float*)d_in[2];
    const float* wv   = (const float*)d_in[3];
    const float* wo   = (const float*)d_in[4];
    const float* fcos = (const float*)d_in[5];
    const float* fsin = (const float*)d_in[6];
    // d_in[7] = mask: causal, computed analytically in attn_fwd.
    float* out = (float*)d_out;

    uint8_t* ws = (uint8_t*)d_ws;
    // layout (bytes):
    //   [0,            16777216)  x_bf   [4096][2048]   -- later reused as att_bf
    //   [16777216,     29360128)  w_bf   [3072][2048]   -- later reused as wo_bf
    //   [29360128,     54525952)  qkv_bf [4096][3072]
    uint16_t* x_bf   = (uint16_t*)(ws);
    uint16_t* w_bf   = (uint16_t*)(ws + 16777216);
    uint16_t* qkv_bf = (uint16_t*)(ws + 29360128);
    uint16_t* att_bf = x_bf;   // alias: x_bf dead after GEMM1
    uint16_t* wo_bf  = w_bf;   // alias: w_bf dead after GEMM1

    // 1) casts
    cvt4<<<(2097152 + 255) / 256, 256, 0, stream>>>(x, x_bf, 2097152);
    build_wqkv<<<(1572864 + 255) / 256, 256, 0, stream>>>(wq, wk, wv, w_bf);

    // 2) QKV projection: [4096][3072] = x_bf @ w_bf^T
    gemm_bt<1><<<dim3(32, 24), 256, 0, stream>>>(x_bf, w_bf, qkv_bf, 4096, 3072, 2048);

    // 3) RoPE on q,k columns
    rope_inplace<<<(4096 * 1280 + 255) / 256, 256, 0, stream>>>(qkv_bf, fcos, fsin);

    // 4) wo cast (into the retired w_bf slot)
    cvt4<<<(1048576 + 255) / 256, 256, 0, stream>>>(wo, wo_bf, 1048576);

    // 5) flash attention -> att_bf [4096][2048]
    attn_fwd<<<2048, 256, 0, stream>>>(qkv_bf, att_bf);

    // 6) O projection -> fp32 out
    gemm_bt<0><<<dim3(32, 16), 256, 0, stream>>>(att_bf, wo_bf, out, 4096, 2048, 2048);
}

// Round 2
// 488.266 us; speedup vs baseline: 1.0783x; 1.0783x over previous
//
#include <hip/hip_runtime.h>
#include <hip/hip_bf16.h>
#include <stdint.h>

// ---------------------------------------------------------------------------
// Attention layer: x->QKV proj -> RoPE -> causal GQA flash attn -> O proj
// B=2 S=2048 D=2048 H=32 KVH=8 HD=64. All GEMMs bf16 MFMA 16x16x32, fp32 accum.
// ---------------------------------------------------------------------------

#define NEG_BIG (-1e9f)
#define SCALE_LOG2 0.18033688011112042f   // (1/sqrt(64)) * log2(e)

typedef __bf16 bf16x8 __attribute__((ext_vector_type(8)));
typedef float f32x4 __attribute__((ext_vector_type(4)));
typedef uint16_t u16x8 __attribute__((ext_vector_type(8)));

__device__ inline uint16_t f2bf(float x) {
    __hip_bfloat16 h = __float2bfloat16(x);
    return __builtin_bit_cast(uint16_t, h);
}
__device__ inline float bf2f(uint16_t u) {
    uint32_t t = (uint32_t)u << 16;
    return __builtin_bit_cast(float, t);
}

__device__ inline void async_cp16(const void* g, void* l) {
    __builtin_amdgcn_global_load_lds(
        (const __attribute__((address_space(1))) uint32_t*)g,
        (__attribute__((address_space(3))) uint32_t*)l,
        16 /*bytes*/, 0 /*offset*/, 0 /*aux*/);
}

// ------------------------- fp32 -> bf16 cast (4/thread) ---------------------
__global__ void cvt4(const float* __restrict__ in, uint16_t* __restrict__ out, int n4) {
    int i = blockIdx.x * blockDim.x + threadIdx.x;
    if (i >= n4) return;
    const float4 v = ((const float4*)in)[i];
    ushort4 o;
    o.x = f2bf(v.x); o.y = f2bf(v.y); o.z = f2bf(v.z); o.w = f2bf(v.w);
    ((ushort4*)out)[i] = o;
}

// ------------------- build concat W = [wq; wk; wv] in bf16 ------------------
__global__ void build_wqkv(const float* __restrict__ wq, const float* __restrict__ wk,
                           const float* __restrict__ wv, uint16_t* __restrict__ out) {
    int i = blockIdx.x * blockDim.x + threadIdx.x;   // one per 4 elements
    if (i >= (3072 * 2048) / 4) return;
    int e = i * 4;
    int row = e >> 11;           // /2048
    int col = e & 2047;
    const float* src = (row < 2048) ? (wq + (long)row * 2048 + col)
                     : (row < 2560) ? (wk + (long)(row - 2048) * 2048 + col)
                                    : (wv + (long)(row - 2560) * 2048 + col);
    const float4 v = *(const float4*)src;
    ushort4 o;
    o.x = f2bf(v.x); o.y = f2bf(v.y); o.z = f2bf(v.z); o.w = f2bf(v.w);
    ((ushort4*)(out + e))[0] = o;
}

// ------------------------------- GEMM (NT) ----------------------------------
// C[m][n] = sum_k A[m][k] * B[n][k];  A:[M][K] bf16, B:[N][K] bf16.
// 128x128 tile, BK=32, 256 threads (4 waves, 2x2), global_load_lds staging.
template <int OUT_BF16>
__global__ __launch_bounds__(256) void gemm_bt(const uint16_t* __restrict__ A,
                                               const uint16_t* __restrict__ Bw,
                                               void* __restrict__ Cout,
                                               int M, int N, int K) {
    __shared__ __align__(16) uint16_t Asm[128 * 32];
    __shared__ __align__(16) uint16_t Bsm[128 * 32];
    const int t = threadIdx.x;
    const int l = t & 63;
    const int w = t >> 6;
    const int wr = w >> 1, wc = w & 1;
    const int c = l & 15, g = l >> 4;
    const long row0 = (long)blockIdx.x * 128;
    const long col0 = (long)blockIdx.y * 128;

    f32x4 acc[4][4] = {};

    const uint16_t* aSrc = A + (row0 + (t >> 2)) * (long)K + (t & 3) * 8;
    const uint16_t* bSrc = Bw + (col0 + (t >> 2)) * (long)K + (t & 3) * 8;
    const long half = 64L * K;

    for (int k0 = 0; k0 < K; k0 += 32) {
        __syncthreads();                       // previous-iter LDS reads done
        async_cp16(aSrc + k0, &Asm[t * 8]);
        async_cp16(aSrc + half + k0, &Asm[2048 + t * 8]);
        async_cp16(bSrc + k0, &Bsm[t * 8]);
        async_cp16(bSrc + half + k0, &Bsm[2048 + t * 8]);
        __syncthreads();                       // staging complete (vmcnt drained)

        bf16x8 aF[4], bF[4];
        const int ko = g * 8;
#pragma unroll
        for (int m = 0; m < 4; ++m)
            aF[m] = *(const bf16x8*)&Asm[(wr * 64 + m * 16 + c) * 32 + ko];
#pragma unroll
        for (int n = 0; n < 4; ++n)
            bF[n] = *(const bf16x8*)&Bsm[(wc * 64 + n * 16 + c) * 32 + ko];
#pragma unroll
        for (int m = 0; m < 4; ++m)
#pragma unroll
            for (int n = 0; n < 4; ++n)
                acc[m][n] = __builtin_amdgcn_mfma_f32_16x16x32_bf16(aF[m], bF[n], acc[m][n], 0, 0, 0);
    }

#pragma unroll
    for (int m = 0; m < 4; ++m) {
        const long rg = row0 + wr * 64 + m * 16 + g * 4;
#pragma unroll
        for (int n = 0; n < 4; ++n) {
            const long cg = col0 + wc * 64 + n * 16 + c;
#pragma unroll
            for (int r = 0; r < 4; ++r) {
                float v = acc[m][n][r];
                if (OUT_BF16)
                    ((uint16_t*)Cout)[(rg + r) * (long)N + cg] = f2bf(v);
                else
                    ((float*)Cout)[(rg + r) * (long)N + cg] = v;
            }
        }
    }
}

// ------------------------------ RoPE in-place -------------------------------
__global__ void rope_inplace(uint16_t* __restrict__ qkv,
                             const float* __restrict__ cosT,
                             const float* __restrict__ sinT) {
    const int PPR = 1280;  // pairs per row: 1024 q + 256 k
    int idx = blockIdx.x * blockDim.x + threadIdx.x;
    if (idx >= 4096 * PPR) return;
    int m = idx / PPR;
    int j = idx - m * PPR;
    int col = (j < 1024) ? (2 * j) : (2048 + 2 * (j - 1024));
    int s = m & 2047;
    int d2 = j & 31;
    float cc = cosT[s * 32 + d2];
    float ss = sinT[s * 32 + d2];
    uint32_t* p = (uint32_t*)(qkv + (long)m * 3072 + col);
    uint32_t v = *p;
    float re = bf2f((uint16_t)(v & 0xffffu));
    float im = bf2f((uint16_t)(v >> 16));
    float orr = re * cc - im * ss;
    float oi = re * ss + im * cc;
    *p = (uint32_t)f2bf(orr) | ((uint32_t)f2bf(oi) << 16);
}

// --------------------------- V transpose pack -------------------------------
// Vt[b][kvh][d(64)][s(2048)] <- qkv[:, 2560 + kvh*64 + d]. One wave per
// (head, 8-s block): lane = d; 8 coalesced 128B row reads, one 16B store.
__global__ void pack_vt(const uint16_t* __restrict__ qkv, uint16_t* __restrict__ Vt) {
    const int wid = (blockIdx.x * blockDim.x + threadIdx.x) >> 6;
    const int lane = threadIdx.x & 63;
    const int head = wid >> 8;          // b*8 + kvh, 0..15
    const int sblk = wid & 255;         // 8-row s block
    const int b = head >> 3, kvh = head & 7;
    const uint16_t* src = qkv + ((long)(b * 2048 + sblk * 8)) * 3072 + 2560 + kvh * 64 + lane;
    u16x8 v;
#pragma unroll
    for (int j = 0; j < 8; ++j) v[j] = src[(long)j * 3072];
    uint16_t* dst = Vt + ((long)head * 64 + lane) * 2048 + sblk * 8;
    *(u16x8*)dst = v;
}

// ---------------------------- flash attention -------------------------------
// block = (b, h, 128-row q tile); 4 waves; each wave owns q rows
// q0..q0+15 (qset 0) and q0+64..q0+79 (qset 1), q0 = qt*128 + w*16.
// KV tile = 64 keys. K read direct from qkv (dense 128B/row), V from Vt.
// Softmax in exp2 domain. No block barrier: Pbuf is per-wave, DS in-order.
__global__ __launch_bounds__(256) void attn_fwd(const uint16_t* __restrict__ qkv,
                                                const uint16_t* __restrict__ Vt,
                                                uint16_t* __restrict__ outb) {
    const int bid = blockIdx.x;
    const int qt = bid & 15;
    const int h = (bid >> 4) & 31;
    const int b = bid >> 9;
    const int kvh = h >> 2;
    const int t = threadIdx.x;
    const int l = t & 63, w = t >> 6;
    const int c = l & 15, g = l >> 4;
    const int q0 = qt * 128 + w * 16;

    __shared__ __align__(16) uint16_t Pbuf[4][2][16][72];   // +pad for banks/align

    // Q fragments: qf[qset][ks]; lane holds Q[q0+qset*64+c][ks*32 + g*8 + j]
    bf16x8 qf[2][2];
#pragma unroll
    for (int qs = 0; qs < 2; ++qs) {
        const uint16_t* qp = qkv + ((long)(b * 2048 + q0 + qs * 64 + c)) * 3072 + h * 64 + g * 8;
        qf[qs][0] = *(const bf16x8*)qp;
        qf[qs][1] = *(const bf16x8*)(qp + 32);
    }

    float m_run[2][4], l_run[2][4];
    f32x4 accO[2][4] = {};
#pragma unroll
    for (int qs = 0; qs < 2; ++qs)
#pragma unroll
        for (int r = 0; r < 4; ++r) { m_run[qs][r] = -1e30f; l_run[qs][r] = 0.f; }

    const uint16_t* kbase = qkv + (long)b * 2048 * 3072 + 2048 + kvh * 64;
    const uint16_t* vbase = Vt + (long)(b * 8 + kvh) * 64 * 2048;
    const int ntiles = 2 * qt + 2;      // 64-key tiles, keys 0..qt*128+127

    for (int tile = 0; tile < ntiles; ++tile) {
        const int k0 = tile * 64;

        // ---- S = Q K^T (both qsets share the K fragments) ----
        f32x4 s[2][4];
#pragma unroll
        for (int n = 0; n < 4; ++n) {
            const uint16_t* kp = kbase + (long)(k0 + n * 16 + c) * 3072 + g * 8;
            const bf16x8 kf0 = *(const bf16x8*)kp;
            const bf16x8 kf1 = *(const bf16x8*)(kp + 32);
#pragma unroll
            for (int qs = 0; qs < 2; ++qs) {
                f32x4 z = {};
                z = __builtin_amdgcn_mfma_f32_16x16x32_bf16(qf[qs][0], kf0, z, 0, 0, 0);
                z = __builtin_amdgcn_mfma_f32_16x16x32_bf16(qf[qs][1], kf1, z, 0, 0, 0);
                s[qs][n] = z;
            }
        }

        // ---- scale to log2 domain + causal mask (only boundary tiles) ----
#pragma unroll
        for (int qs = 0; qs < 2; ++qs) {
            const int rowb = q0 + qs * 64;
            if (k0 + 63 > rowb) {
#pragma unroll
                for (int n = 0; n < 4; ++n) {
                    const int key = k0 + n * 16 + c;
#pragma unroll
                    for (int r = 0; r < 4; ++r)
                        s[qs][n][r] = s[qs][n][r] * SCALE_LOG2 +
                                      (key > rowb + 4 * g + r ? NEG_BIG : 0.f);
                }
            } else {
#pragma unroll
                for (int n = 0; n < 4; ++n)
#pragma unroll
                    for (int r = 0; r < 4; ++r)
                        s[qs][n][r] = s[qs][n][r] * SCALE_LOG2;
            }
        }

        // ---- online softmax (16-lane row reduce), write P to LDS ----
        float alph[2][4];
#pragma unroll
        for (int qs = 0; qs < 2; ++qs) {
#pragma unroll
            for (int r = 0; r < 4; ++r) {
                float vm = fmaxf(fmaxf(s[qs][0][r], s[qs][1][r]),
                                 fmaxf(s[qs][2][r], s[qs][3][r]));
                vm = fmaxf(vm, __shfl_xor(vm, 1));
                vm = fmaxf(vm, __shfl_xor(vm, 2));
                vm = fmaxf(vm, __shfl_xor(vm, 4));
                vm = fmaxf(vm, __shfl_xor(vm, 8));
                const float mnew = fmaxf(m_run[qs][r], vm);
                alph[qs][r] = __builtin_amdgcn_exp2f(m_run[qs][r] - mnew);
                m_run[qs][r] = mnew;
                float sum = 0.f;
#pragma unroll
                for (int n = 0; n < 4; ++n) {
                    const float p = __builtin_amdgcn_exp2f(s[qs][n][r] - mnew);
                    sum += p;
                    Pbuf[w][qs][4 * g + r][n * 16 + c] = f2bf(p);
                }
                sum += __shfl_xor(sum, 1);
                sum += __shfl_xor(sum, 2);
                sum += __shfl_xor(sum, 4);
                sum += __shfl_xor(sum, 8);
                l_run[qs][r] = l_run[qs][r] * alph[qs][r] + sum;
            }
        }
#pragma unroll
        for (int qs = 0; qs < 2; ++qs)
#pragma unroll
            for (int nn = 0; nn < 4; ++nn)
#pragma unroll
                for (int r = 0; r < 4; ++r)
                    accO[qs][nn][r] *= alph[qs][r];

        asm volatile("" ::: "memory");   // pin LDS write->read order (DS is in-order per wave)

        bf16x8 pf[2][2];
#pragma unroll
        for (int qs = 0; qs < 2; ++qs) {
            pf[qs][0] = *(const bf16x8*)&Pbuf[w][qs][c][g * 8];
            pf[qs][1] = *(const bf16x8*)&Pbuf[w][qs][c][32 + g * 8];
        }

        // ---- PV: V^T fragments from Vt (dense 16B vector loads) ----
#pragma unroll
        for (int nn = 0; nn < 4; ++nn) {
            const uint16_t* vp = vbase + (long)(nn * 16 + c) * 2048 + k0 + g * 8;
            const bf16x8 vf0 = *(const bf16x8*)vp;
            const bf16x8 vf1 = *(const bf16x8*)(vp + 32);
#pragma unroll
            for (int qs = 0; qs < 2; ++qs) {
                accO[qs][nn] = __builtin_amdgcn_mfma_f32_16x16x32_bf16(pf[qs][0], vf0, accO[qs][nn], 0, 0, 0);
                accO[qs][nn] = __builtin_amdgcn_mfma_f32_16x16x32_bf16(pf[qs][1], vf1, accO[qs][nn], 0, 0, 0);
            }
        }
    }

    // ---- epilogue ----
#pragma unroll
    for (int qs = 0; qs < 2; ++qs)
#pragma unroll
        for (int nn = 0; nn < 4; ++nn)
#pragma unroll
            for (int r = 0; r < 4; ++r) {
                const int qg = q0 + qs * 64 + 4 * g + r;
                const float o = accO[qs][nn][r] / l_run[qs][r];
                outb[(long)(b * 2048 + qg) * 2048 + h * 64 + nn * 16 + c] = f2bf(o);
            }
}

// ---------------------------------------------------------------------------
extern "C" void kernel_launch(void* const* d_in, const int* in_sizes, int n_in,
                              void* d_out, int out_size, void* d_ws, size_t ws_size,
                              hipStream_t stream) {
    const float* x    = (const float*)d_in[0];
    const float* wq   = (const float*)d_in[1];
    const float* wk   = (const float*)d_in[2];
    const float* wv   = (const float*)d_in[3];
    const float* wo   = (const float*)d_in[4];
    const float* fcos = (const float*)d_in[5];
    const float* fsin = (const float*)d_in[6];
    // d_in[7] = mask: causal, computed analytically in attn_fwd.
    float* out = (float*)d_out;

    uint8_t* ws = (uint8_t*)d_ws;
    // layout (bytes), total 52 MB:
    //   [0,        16777216)  x_bf [4096][2048]        -- reused as att_bf
    //   [16777216, 29360128)  w_bf [3072][2048]        -- reused: wo_bf (8MB) + Vt (4MB)
    //   [29360128, 54525952)  qkv_bf [4096][3072]
    uint16_t* x_bf   = (uint16_t*)(ws);
    uint16_t* w_bf   = (uint16_t*)(ws + 16777216);
    uint16_t* qkv_bf = (uint16_t*)(ws + 29360128);
    uint16_t* att_bf = x_bf;                            // alias after GEMM1
    uint16_t* wo_bf  = w_bf;                            // alias after GEMM1
    uint16_t* Vt     = (uint16_t*)(ws + 16777216 + 8388608);  // alias after GEMM1

    // 1) casts
    cvt4<<<(2097152 + 255) / 256, 256, 0, stream>>>(x, x_bf, 2097152);
    build_wqkv<<<(1572864 + 255) / 256, 256, 0, stream>>>(wq, wk, wv, w_bf);

    // 2) QKV projection: [4096][3072] = x_bf @ w_bf^T
    gemm_bt<1><<<dim3(32, 24), 256, 0, stream>>>(x_bf, w_bf, qkv_bf, 4096, 3072, 2048);

    // 3) RoPE on q,k columns
    rope_inplace<<<(4096 * 1280 + 255) / 256, 256, 0, stream>>>(qkv_bf, fcos, fsin);

    // 4) pack V^T (w_bf weights dead now), wo cast
    pack_vt<<<1024, 256, 0, stream>>>(qkv_bf, Vt);
    cvt4<<<(1048576 + 255) / 256, 256, 0, stream>>>(wo, wo_bf, 1048576);

    // 5) flash attention -> att_bf [4096][2048]
    attn_fwd<<<1024, 256, 0, stream>>>(qkv_bf, Vt, att_bf);

    // 6) O projection -> fp32 out
    gemm_bt<0><<<dim3(32, 16), 256, 0, stream>>>(att_bf, wo_bf, out, 4096, 2048, 2048);
}

// Round 3
// 315.799 us; speedup vs baseline: 1.6672x; 1.5461x over previous
//
#include <hip/hip_runtime.h>
#include <hip/hip_bf16.h>
#include <stdint.h>

// ---------------------------------------------------------------------------
// Attention layer: x->QKV proj -> RoPE -> causal GQA flash attn -> O proj
// B=2 S=2048 D=2048 H=32 KVH=8 HD=64. All GEMMs bf16 MFMA 16x16x32, fp32 accum.
// ---------------------------------------------------------------------------

#define NEG_BIG (-1e9f)
#define SCALE_LOG2 0.18033688011112042f   // (1/sqrt(64)) * log2(e)

typedef __bf16 bf16x8 __attribute__((ext_vector_type(8)));
typedef float f32x4 __attribute__((ext_vector_type(4)));
typedef uint16_t u16x8 __attribute__((ext_vector_type(8)));

__device__ inline uint16_t f2bf(float x) {
    __hip_bfloat16 h = __float2bfloat16(x);
    return __builtin_bit_cast(uint16_t, h);
}
__device__ inline float bf2f(uint16_t u) {
    uint32_t t = (uint32_t)u << 16;
    return __builtin_bit_cast(float, t);
}

__device__ inline void async_cp16(const void* g, void* l) {
    __builtin_amdgcn_global_load_lds(
        (const __attribute__((address_space(1))) uint32_t*)g,
        (__attribute__((address_space(3))) uint32_t*)l,
        16 /*bytes*/, 0 /*offset*/, 0 /*aux*/);
}

// ------------------------- fp32 -> bf16 cast (4/thread) ---------------------
__global__ void cvt4(const float* __restrict__ in, uint16_t* __restrict__ out, int n4) {
    int i = blockIdx.x * blockDim.x + threadIdx.x;
    if (i >= n4) return;
    const float4 v = ((const float4*)in)[i];
    ushort4 o;
    o.x = f2bf(v.x); o.y = f2bf(v.y); o.z = f2bf(v.z); o.w = f2bf(v.w);
    ((ushort4*)out)[i] = o;
}

// ------------------- build concat W = [wq; wk; wv] in bf16 ------------------
__global__ void build_wqkv(const float* __restrict__ wq, const float* __restrict__ wk,
                           const float* __restrict__ wv, uint16_t* __restrict__ out) {
    int i = blockIdx.x * blockDim.x + threadIdx.x;   // one per 4 elements
    if (i >= (3072 * 2048) / 4) return;
    int e = i * 4;
    int row = e >> 11;           // /2048
    int col = e & 2047;
    const float* src = (row < 2048) ? (wq + (long)row * 2048 + col)
                     : (row < 2560) ? (wk + (long)(row - 2048) * 2048 + col)
                                    : (wv + (long)(row - 2560) * 2048 + col);
    const float4 v = *(const float4*)src;
    ushort4 o;
    o.x = f2bf(v.x); o.y = f2bf(v.y); o.z = f2bf(v.z); o.w = f2bf(v.w);
    ((ushort4*)(out + e))[0] = o;
}

// ------------------------------- GEMM (NT) ----------------------------------
// C[m][n] = sum_k A[m][k] * B[n][k];  A:[M][K] bf16, B:[N][K] bf16.
// 128x128 tile, BK=32, 256 threads (4 waves, 2x2), global_load_lds staging.
template <int OUT_BF16>
__global__ __launch_bounds__(256) void gemm_bt(const uint16_t* __restrict__ A,
                                               const uint16_t* __restrict__ Bw,
                                               void* __restrict__ Cout,
                                               int M, int N, int K) {
    __shared__ __align__(16) uint16_t Asm[128 * 32];
    __shared__ __align__(16) uint16_t Bsm[128 * 32];
    const int t = threadIdx.x;
    const int l = t & 63;
    const int w = t >> 6;
    const int wr = w >> 1, wc = w & 1;
    const int c = l & 15, g = l >> 4;
    const long row0 = (long)blockIdx.x * 128;
    const long col0 = (long)blockIdx.y * 128;

    f32x4 acc[4][4] = {};

    const uint16_t* aSrc = A + (row0 + (t >> 2)) * (long)K + (t & 3) * 8;
    const uint16_t* bSrc = Bw + (col0 + (t >> 2)) * (long)K + (t & 3) * 8;
    const long half = 64L * K;

    for (int k0 = 0; k0 < K; k0 += 32) {
        __syncthreads();                       // previous-iter LDS reads done
        async_cp16(aSrc + k0, &Asm[t * 8]);
        async_cp16(aSrc + half + k0, &Asm[2048 + t * 8]);
        async_cp16(bSrc + k0, &Bsm[t * 8]);
        async_cp16(bSrc + half + k0, &Bsm[2048 + t * 8]);
        __syncthreads();                       // staging complete (vmcnt drained)

        bf16x8 aF[4], bF[4];
        const int ko = g * 8;
#pragma unroll
        for (int m = 0; m < 4; ++m)
            aF[m] = *(const bf16x8*)&Asm[(wr * 64 + m * 16 + c) * 32 + ko];
#pragma unroll
        for (int n = 0; n < 4; ++n)
            bF[n] = *(const bf16x8*)&Bsm[(wc * 64 + n * 16 + c) * 32 + ko];
#pragma unroll
        for (int m = 0; m < 4; ++m)
#pragma unroll
            for (int n = 0; n < 4; ++n)
                acc[m][n] = __builtin_amdgcn_mfma_f32_16x16x32_bf16(aF[m], bF[n], acc[m][n], 0, 0, 0);
    }

#pragma unroll
    for (int m = 0; m < 4; ++m) {
        const long rg = row0 + wr * 64 + m * 16 + g * 4;
#pragma unroll
        for (int n = 0; n < 4; ++n) {
            const long cg = col0 + wc * 64 + n * 16 + c;
#pragma unroll
            for (int r = 0; r < 4; ++r) {
                float v = acc[m][n][r];
                if (OUT_BF16)
                    ((uint16_t*)Cout)[(rg + r) * (long)N + cg] = f2bf(v);
                else
                    ((float*)Cout)[(rg + r) * (long)N + cg] = v;
            }
        }
    }
}

// ------------------------------ RoPE in-place -------------------------------
__global__ void rope_inplace(uint16_t* __restrict__ qkv,
                             const float* __restrict__ cosT,
                             const float* __restrict__ sinT) {
    const int PPR = 1280;  // pairs per row: 1024 q + 256 k
    int idx = blockIdx.x * blockDim.x + threadIdx.x;
    if (idx >= 4096 * PPR) return;
    int m = idx / PPR;
    int j = idx - m * PPR;
    int col = (j < 1024) ? (2 * j) : (2048 + 2 * (j - 1024));
    int s = m & 2047;
    int d2 = j & 31;
    float cc = cosT[s * 32 + d2];
    float ss = sinT[s * 32 + d2];
    uint32_t* p = (uint32_t*)(qkv + (long)m * 3072 + col);
    uint32_t v = *p;
    float re = bf2f((uint16_t)(v & 0xffffu));
    float im = bf2f((uint16_t)(v >> 16));
    float orr = re * cc - im * ss;
    float oi = re * ss + im * cc;
    *p = (uint32_t)f2bf(orr) | ((uint32_t)f2bf(oi) << 16);
}

// --------------------------- V transpose pack -------------------------------
// Vt[b][kvh][d(64)][s(2048)] <- qkv[:, 2560 + kvh*64 + d].
__global__ void pack_vt(const uint16_t* __restrict__ qkv, uint16_t* __restrict__ Vt) {
    const int wid = (blockIdx.x * blockDim.x + threadIdx.x) >> 6;
    const int lane = threadIdx.x & 63;
    const int head = wid >> 8;          // b*8 + kvh, 0..15
    const int sblk = wid & 255;         // 8-row s block
    const int b = head >> 3, kvh = head & 7;
    const uint16_t* src = qkv + ((long)(b * 2048 + sblk * 8)) * 3072 + 2560 + kvh * 64 + lane;
    u16x8 v;
#pragma unroll
    for (int j = 0; j < 8; ++j) v[j] = src[(long)j * 3072];
    uint16_t* dst = Vt + ((long)head * 64 + lane) * 2048 + sblk * 8;
    *(u16x8*)dst = v;
}

// ---------------------------- flash attention -------------------------------
// 512 blocks x 512 threads (8 waves). Block = (b, h, q-tile PAIR p):
// waves 0-3 -> q-tile p (128 rows), waves 4-7 -> q-tile 15-p. Every block
// does exactly (2p+2)+(2(15-p)+2) = 36 64-key tile-iters -> CU load uniform
// regardless of dispatch mapping. Per wave: 16 rows x 2 qsets (rows q0,q0+64).
// K read direct from qkv rows, V from pre-transposed Vt; both batch-staged
// into registers so softmax VALU hides V latency (T14-lite).
__global__ __launch_bounds__(512, 2) void attn_fwd(const uint16_t* __restrict__ qkv,
                                                   const uint16_t* __restrict__ Vt,
                                                   uint16_t* __restrict__ outb) {
    const int bid = blockIdx.x;
    const int p = bid & 7;
    const int h = (bid >> 3) & 31;
    const int b = bid >> 8;
    const int kvh = h >> 2;
    const int t = threadIdx.x;
    const int l = t & 63, w = t >> 6;
    const int grp = w >> 2, ww = w & 3;
    const int qt = grp ? (15 - p) : p;
    const int c = l & 15, g = l >> 4;
    const int q0 = qt * 128 + ww * 16;

    __shared__ __align__(16) uint16_t Pbuf[8][2][16][72];

    // Q fragments: qf[qset][ks]; lane holds Q[q0+qset*64+c][ks*32 + g*8 + j]
    bf16x8 qf[2][2];
#pragma unroll
    for (int qs = 0; qs < 2; ++qs) {
        const uint16_t* qp = qkv + ((long)(b * 2048 + q0 + qs * 64 + c)) * 3072 + h * 64 + g * 8;
        qf[qs][0] = *(const bf16x8*)qp;
        qf[qs][1] = *(const bf16x8*)(qp + 32);
    }

    float m_run[2][4], l_run[2][4];
    f32x4 accO[2][4] = {};
#pragma unroll
    for (int qs = 0; qs < 2; ++qs)
#pragma unroll
        for (int r = 0; r < 4; ++r) { m_run[qs][r] = -1e30f; l_run[qs][r] = 0.f; }

    const uint16_t* kbase = qkv + (long)b * 2048 * 3072 + 2048 + kvh * 64;
    const uint16_t* vbase = Vt + (long)(b * 8 + kvh) * 64 * 2048;
    const int ntiles = 2 * qt + 2;      // 64-key tiles, keys 0..qt*128+127

    for (int tile = 0; tile < ntiles; ++tile) {
        const int k0 = tile * 64;

        // ---- batch-load all K fragments (one latency exposure) ----
        bf16x8 kf[4][2];
#pragma unroll
        for (int n = 0; n < 4; ++n) {
            const uint16_t* kp = kbase + (long)(k0 + n * 16 + c) * 3072 + g * 8;
            kf[n][0] = *(const bf16x8*)kp;
            kf[n][1] = *(const bf16x8*)(kp + 32);
        }

        // ---- S = Q K^T (both qsets share the K fragments) ----
        f32x4 s[2][4];
#pragma unroll
        for (int n = 0; n < 4; ++n)
#pragma unroll
            for (int qs = 0; qs < 2; ++qs) {
                f32x4 z = {};
                z = __builtin_amdgcn_mfma_f32_16x16x32_bf16(qf[qs][0], kf[n][0], z, 0, 0, 0);
                z = __builtin_amdgcn_mfma_f32_16x16x32_bf16(qf[qs][1], kf[n][1], z, 0, 0, 0);
                s[qs][n] = z;
            }

        // ---- issue all V loads now; softmax below hides their latency ----
        bf16x8 vf[4][2];
#pragma unroll
        for (int nn = 0; nn < 4; ++nn) {
            const uint16_t* vp = vbase + (long)(nn * 16 + c) * 2048 + k0 + g * 8;
            vf[nn][0] = *(const bf16x8*)vp;
            vf[nn][1] = *(const bf16x8*)(vp + 32);
        }

        // ---- scale to log2 domain + causal mask (only boundary tiles) ----
#pragma unroll
        for (int qs = 0; qs < 2; ++qs) {
            const int rowb = q0 + qs * 64;
            if (k0 + 63 > rowb) {
#pragma unroll
                for (int n = 0; n < 4; ++n) {
                    const int key = k0 + n * 16 + c;
#pragma unroll
                    for (int r = 0; r < 4; ++r)
                        s[qs][n][r] = s[qs][n][r] * SCALE_LOG2 +
                                      (key > rowb + 4 * g + r ? NEG_BIG : 0.f);
                }
            } else {
#pragma unroll
                for (int n = 0; n < 4; ++n)
#pragma unroll
                    for (int r = 0; r < 4; ++r)
                        s[qs][n][r] = s[qs][n][r] * SCALE_LOG2;
            }
        }

        // ---- online softmax (16-lane row reduce), write P to LDS ----
        float alph[2][4];
#pragma unroll
        for (int qs = 0; qs < 2; ++qs) {
#pragma unroll
            for (int r = 0; r < 4; ++r) {
                float vm = fmaxf(fmaxf(s[qs][0][r], s[qs][1][r]),
                                 fmaxf(s[qs][2][r], s[qs][3][r]));
                vm = fmaxf(vm, __shfl_xor(vm, 1));
                vm = fmaxf(vm, __shfl_xor(vm, 2));
                vm = fmaxf(vm, __shfl_xor(vm, 4));
                vm = fmaxf(vm, __shfl_xor(vm, 8));
                const float mnew = fmaxf(m_run[qs][r], vm);
                alph[qs][r] = __builtin_amdgcn_exp2f(m_run[qs][r] - mnew);
                m_run[qs][r] = mnew;
                float sum = 0.f;
#pragma unroll
                for (int n = 0; n < 4; ++n) {
                    const float pv = __builtin_amdgcn_exp2f(s[qs][n][r] - mnew);
                    sum += pv;
                    Pbuf[w][qs][4 * g + r][n * 16 + c] = f2bf(pv);
                }
                sum += __shfl_xor(sum, 1);
                sum += __shfl_xor(sum, 2);
                sum += __shfl_xor(sum, 4);
                sum += __shfl_xor(sum, 8);
                l_run[qs][r] = l_run[qs][r] * alph[qs][r] + sum;
            }
        }
#pragma unroll
        for (int qs = 0; qs < 2; ++qs)
#pragma unroll
            for (int nn = 0; nn < 4; ++nn)
#pragma unroll
                for (int r = 0; r < 4; ++r)
                    accO[qs][nn][r] *= alph[qs][r];

        asm volatile("" ::: "memory");   // pin LDS write->read order (DS in-order per wave)

        bf16x8 pf[2][2];
#pragma unroll
        for (int qs = 0; qs < 2; ++qs) {
            pf[qs][0] = *(const bf16x8*)&Pbuf[w][qs][c][g * 8];
            pf[qs][1] = *(const bf16x8*)&Pbuf[w][qs][c][32 + g * 8];
        }

        // ---- PV from pre-staged V fragments ----
#pragma unroll
        for (int nn = 0; nn < 4; ++nn)
#pragma unroll
            for (int qs = 0; qs < 2; ++qs) {
                accO[qs][nn] = __builtin_amdgcn_mfma_f32_16x16x32_bf16(pf[qs][0], vf[nn][0], accO[qs][nn], 0, 0, 0);
                accO[qs][nn] = __builtin_amdgcn_mfma_f32_16x16x32_bf16(pf[qs][1], vf[nn][1], accO[qs][nn], 0, 0, 0);
            }
    }

    // ---- epilogue ----
#pragma unroll
    for (int qs = 0; qs < 2; ++qs)
#pragma unroll
        for (int nn = 0; nn < 4; ++nn)
#pragma unroll
            for (int r = 0; r < 4; ++r) {
                const int qg = q0 + qs * 64 + 4 * g + r;
                const float o = accO[qs][nn][r] / l_run[qs][r];
                outb[(long)(b * 2048 + qg) * 2048 + h * 64 + nn * 16 + c] = f2bf(o);
            }
}

// ---------------------------------------------------------------------------
extern "C" void kernel_launch(void* const* d_in, const int* in_sizes, int n_in,
                              void* d_out, int out_size, void* d_ws, size_t ws_size,
                              hipStream_t stream) {
    const float* x    = (const float*)d_in[0];
    const float* wq   = (const float*)d_in[1];
    const float* wk   = (const float*)d_in[2];
    const float* wv   = (const float*)d_in[3];
    const float* wo   = (const float*)d_in[4];
    const float* fcos = (const float*)d_in[5];
    const float* fsin = (const float*)d_in[6];
    // d_in[7] = mask: causal, computed analytically in attn_fwd.
    float* out = (float*)d_out;

    uint8_t* ws = (uint8_t*)d_ws;
    // layout (bytes), total 52 MB:
    //   [0,        16777216)  x_bf [4096][2048]        -- reused as att_bf
    //   [16777216, 29360128)  w_bf [3072][2048]        -- reused: wo_bf (8MB) + Vt (4MB)
    //   [29360128, 54525952)  qkv_bf [4096][3072]
    uint16_t* x_bf   = (uint16_t*)(ws);
    uint16_t* w_bf   = (uint16_t*)(ws + 16777216);
    uint16_t* qkv_bf = (uint16_t*)(ws + 29360128);
    uint16_t* att_bf = x_bf;                            // alias after GEMM1
    uint16_t* wo_bf  = w_bf;                            // alias after GEMM1
    uint16_t* Vt     = (uint16_t*)(ws + 16777216 + 8388608);  // alias after GEMM1

    // 1) casts
    cvt4<<<(2097152 + 255) / 256, 256, 0, stream>>>(x, x_bf, 2097152);
    build_wqkv<<<(1572864 + 255) / 256, 256, 0, stream>>>(wq, wk, wv, w_bf);

    // 2) QKV projection: [4096][3072] = x_bf @ w_bf^T
    gemm_bt<1><<<dim3(32, 24), 256, 0, stream>>>(x_bf, w_bf, qkv_bf, 4096, 3072, 2048);

    // 3) RoPE on q,k columns
    rope_inplace<<<(4096 * 1280 + 255) / 256, 256, 0, stream>>>(qkv_bf, fcos, fsin);

    // 4) pack V^T (w_bf weights dead now), wo cast
    pack_vt<<<1024, 256, 0, stream>>>(qkv_bf, Vt);
    cvt4<<<(1048576 + 255) / 256, 256, 0, stream>>>(wo, wo_bf, 1048576);

    // 5) flash attention -> att_bf [4096][2048]
    attn_fwd<<<512, 512, 0, stream>>>(qkv_bf, Vt, att_bf);

    // 6) O projection -> fp32 out
    gemm_bt<0><<<dim3(32, 16), 256, 0, stream>>>(att_bf, wo_bf, out, 4096, 2048, 2048);
}

// Round 4
// 281.657 us; speedup vs baseline: 1.8693x; 1.1212x over previous
//
#include <hip/hip_runtime.h>
#include <hip/hip_bf16.h>
#include <stdint.h>

// ---------------------------------------------------------------------------
// Attention layer: x->QKV proj -> RoPE -> causal GQA flash attn -> O proj
// B=2 S=2048 D=2048 H=32 KVH=8 HD=64. GEMMs bf16 MFMA 16x16x32; attention
// uses 32x32x16 with swapped-operand QK^T (in-register softmax, zero LDS).
// ---------------------------------------------------------------------------

#define NEG_BIG (-1e9f)
#define SCALE_LOG2 0.18033688011112042f   // (1/sqrt(64)) * log2(e)

typedef __bf16 bf16x8 __attribute__((ext_vector_type(8)));
typedef float f32x4 __attribute__((ext_vector_type(4)));
typedef float f32x16 __attribute__((ext_vector_type(16)));
typedef uint16_t u16x8 __attribute__((ext_vector_type(8)));
typedef uint32_t u32x4 __attribute__((ext_vector_type(4)));

__device__ inline uint16_t f2bf(float x) {
    __hip_bfloat16 h = __float2bfloat16(x);
    return __builtin_bit_cast(uint16_t, h);
}
__device__ inline float bf2f(uint16_t u) {
    uint32_t t = (uint32_t)u << 16;
    return __builtin_bit_cast(float, t);
}

__device__ inline void async_cp16(const void* g, void* l) {
    __builtin_amdgcn_global_load_lds(
        (const __attribute__((address_space(1))) uint32_t*)g,
        (__attribute__((address_space(3))) uint32_t*)l,
        16 /*bytes*/, 0 /*offset*/, 0 /*aux*/);
}

// ------------------------- fp32 -> bf16 cast (4/thread) ---------------------
__global__ void cvt4(const float* __restrict__ in, uint16_t* __restrict__ out, int n4) {
    int i = blockIdx.x * blockDim.x + threadIdx.x;
    if (i >= n4) return;
    const float4 v = ((const float4*)in)[i];
    ushort4 o;
    o.x = f2bf(v.x); o.y = f2bf(v.y); o.z = f2bf(v.z); o.w = f2bf(v.w);
    ((ushort4*)out)[i] = o;
}

// ------------------- build concat W = [wq; wk; wv] in bf16 ------------------
__global__ void build_wqkv(const float* __restrict__ wq, const float* __restrict__ wk,
                           const float* __restrict__ wv, uint16_t* __restrict__ out) {
    int i = blockIdx.x * blockDim.x + threadIdx.x;   // one per 4 elements
    if (i >= (3072 * 2048) / 4) return;
    int e = i * 4;
    int row = e >> 11;           // /2048
    int col = e & 2047;
    const float* src = (row < 2048) ? (wq + (long)row * 2048 + col)
                     : (row < 2560) ? (wk + (long)(row - 2048) * 2048 + col)
                                    : (wv + (long)(row - 2560) * 2048 + col);
    const float4 v = *(const float4*)src;
    ushort4 o;
    o.x = f2bf(v.x); o.y = f2bf(v.y); o.z = f2bf(v.z); o.w = f2bf(v.w);
    ((ushort4*)(out + e))[0] = o;
}

// ------------------------------- GEMM (NT) ----------------------------------
// C[m][n] = sum_k A[m][k] * B[n][k];  A:[M][K] bf16, B:[N][K] bf16.
// 128x128 tile, BK=32, 256 threads (4 waves, 2x2), global_load_lds staging.
template <int OUT_BF16>
__global__ __launch_bounds__(256) void gemm_bt(const uint16_t* __restrict__ A,
                                               const uint16_t* __restrict__ Bw,
                                               void* __restrict__ Cout,
                                               int M, int N, int K) {
    __shared__ __align__(16) uint16_t Asm[128 * 32];
    __shared__ __align__(16) uint16_t Bsm[128 * 32];
    const int t = threadIdx.x;
    const int l = t & 63;
    const int w = t >> 6;
    const int wr = w >> 1, wc = w & 1;
    const int c = l & 15, g = l >> 4;
    const long row0 = (long)blockIdx.x * 128;
    const long col0 = (long)blockIdx.y * 128;

    f32x4 acc[4][4] = {};

    const uint16_t* aSrc = A + (row0 + (t >> 2)) * (long)K + (t & 3) * 8;
    const uint16_t* bSrc = Bw + (col0 + (t >> 2)) * (long)K + (t & 3) * 8;
    const long half = 64L * K;

    for (int k0 = 0; k0 < K; k0 += 32) {
        __syncthreads();                       // previous-iter LDS reads done
        async_cp16(aSrc + k0, &Asm[t * 8]);
        async_cp16(aSrc + half + k0, &Asm[2048 + t * 8]);
        async_cp16(bSrc + k0, &Bsm[t * 8]);
        async_cp16(bSrc + half + k0, &Bsm[2048 + t * 8]);
        __syncthreads();                       // staging complete (vmcnt drained)

        bf16x8 aF[4], bF[4];
        const int ko = g * 8;
#pragma unroll
        for (int m = 0; m < 4; ++m)
            aF[m] = *(const bf16x8*)&Asm[(wr * 64 + m * 16 + c) * 32 + ko];
#pragma unroll
        for (int n = 0; n < 4; ++n)
            bF[n] = *(const bf16x8*)&Bsm[(wc * 64 + n * 16 + c) * 32 + ko];
#pragma unroll
        for (int m = 0; m < 4; ++m)
#pragma unroll
            for (int n = 0; n < 4; ++n)
                acc[m][n] = __builtin_amdgcn_mfma_f32_16x16x32_bf16(aF[m], bF[n], acc[m][n], 0, 0, 0);
    }

#pragma unroll
    for (int m = 0; m < 4; ++m) {
        const long rg = row0 + wr * 64 + m * 16 + g * 4;
#pragma unroll
        for (int n = 0; n < 4; ++n) {
            const long cg = col0 + wc * 64 + n * 16 + c;
#pragma unroll
            for (int r = 0; r < 4; ++r) {
                float v = acc[m][n][r];
                if (OUT_BF16)
                    ((uint16_t*)Cout)[(rg + r) * (long)N + cg] = f2bf(v);
                else
                    ((float*)Cout)[(rg + r) * (long)N + cg] = v;
            }
        }
    }
}

// ------------------------------ RoPE in-place -------------------------------
__global__ void rope_inplace(uint16_t* __restrict__ qkv,
                             const float* __restrict__ cosT,
                             const float* __restrict__ sinT) {
    const int PPR = 1280;  // pairs per row: 1024 q + 256 k
    int idx = blockIdx.x * blockDim.x + threadIdx.x;
    if (idx >= 4096 * PPR) return;
    int m = idx / PPR;
    int j = idx - m * PPR;
    int col = (j < 1024) ? (2 * j) : (2048 + 2 * (j - 1024));
    int s = m & 2047;
    int d2 = j & 31;
    float cc = cosT[s * 32 + d2];
    float ss = sinT[s * 32 + d2];
    uint32_t* p = (uint32_t*)(qkv + (long)m * 3072 + col);
    uint32_t v = *p;
    float re = bf2f((uint16_t)(v & 0xffffu));
    float im = bf2f((uint16_t)(v >> 16));
    float orr = re * cc - im * ss;
    float oi = re * ss + im * cc;
    *p = (uint32_t)f2bf(orr) | ((uint32_t)f2bf(oi) << 16);
}

// --------------------------- V transpose pack -------------------------------
// Vt[b][kvh][d(64)][s(2048)] <- qkv[:, 2560 + kvh*64 + d].
__global__ void pack_vt(const uint16_t* __restrict__ qkv, uint16_t* __restrict__ Vt) {
    const int wid = (blockIdx.x * blockDim.x + threadIdx.x) >> 6;
    const int lane = threadIdx.x & 63;
    const int head = wid >> 8;          // b*8 + kvh, 0..15
    const int sblk = wid & 255;         // 8-row s block
    const int b = head >> 3, kvh = head & 7;
    const uint16_t* src = qkv + ((long)(b * 2048 + sblk * 8)) * 3072 + 2560 + kvh * 64 + lane;
    u16x8 v;
#pragma unroll
    for (int j = 0; j < 8; ++j) v[j] = src[(long)j * 3072];
    uint16_t* dst = Vt + ((long)head * 64 + lane) * 2048 + sblk * 8;
    *(u16x8*)dst = v;
}

// ---------------------------- flash attention -------------------------------
// 1024 blocks x 256 threads (4 waves). Block = (b, h, 64-row q-tile PAIR p):
// waves 0-1 -> q-tile p, waves 2-3 -> q-tile 31-p (block total = 130 32-key
// wave-tiles, uniform). Each wave owns 32 q-rows; per lane-pair (l, l+32) one
// q-row is fully in-register:
//   Swapped QK^T: S^T = mfma_32x32x16(A=K, B=Q) -> lane holds S[q=l&31][key]
//   for 16 of 32 keys (partner lane has the other 16). Softmax = 15 in-lane
//   fmax + 1 shfl_xor(32); P stays in registers; P^T B-fragments assembled
//   via pack + 8 shfl_xor(32) + selects (T12-style). PV: O^T = mfma(V^T, P^T)
//   with V^T A-fragments vector-loaded from pre-transposed Vt. Zero LDS.
__global__ __launch_bounds__(256, 3) void attn_fwd(const uint16_t* __restrict__ qkv,
                                                   const uint16_t* __restrict__ Vt,
                                                   uint16_t* __restrict__ outb) {
    const int bid = blockIdx.x;
    const int p = bid & 15;
    const int h = (bid >> 4) & 31;
    const int b = bid >> 9;
    const int kvh = h >> 2;
    const int t = threadIdx.x;
    const int l = t & 63, w = t >> 6;
    const int grp = w >> 1, ww = w & 1;
    const int qt = grp ? (31 - p) : p;          // 64-row q tile
    const int q0 = qt * 64 + ww * 32;           // this wave's first q row
    const int lq = l & 31, hi = l >> 5;
    const int q = q0 + lq;

    // Q B-fragments: qf[s] holds Q[q][d = 16s + 8*hi + j], j=0..7
    const uint16_t* qrow = qkv + (long)(b * 2048 + q) * 3072 + h * 64 + 8 * hi;
    bf16x8 qf[4];
#pragma unroll
    for (int s = 0; s < 4; ++s) qf[s] = *(const bf16x8*)(qrow + 16 * s);

    float m_run = -1e30f, l_run = 0.f;
    f32x16 accO[2] = {};                         // O^T[d = nd*32 + roff][q]

    const uint16_t* kbase = qkv + (long)b * 2048 * 3072 + 2048 + kvh * 64 + 8 * hi;
    const uint16_t* vbase = Vt + ((long)(b * 8 + kvh) * 64 + lq) * 2048;
    const int ntiles = 2 * qt + ww + 1;          // 32-key tiles, exact per wave

    for (int tile = 0; tile < ntiles; ++tile) {
        const int k0 = tile * 32;

        // ---- K A-fragments: kf[s] = K[key=k0+lq][d = 16s + 8hi + j] ----
        const uint16_t* krow = kbase + (long)(k0 + lq) * 3072;
        bf16x8 kf[4];
#pragma unroll
        for (int s = 0; s < 4; ++s) kf[s] = *(const bf16x8*)(krow + 16 * s);

        // ---- S^T = K Q^T (lane: q = lq, key = k0 + (reg&3)+4hi+8(reg>>2)) --
        f32x16 st = {};
#pragma unroll
        for (int s = 0; s < 4; ++s)
            st = __builtin_amdgcn_mfma_f32_32x32x16_bf16(kf[s], qf[s], st, 0, 0, 0);

        // ---- V^T A-fragments (issue early; softmax hides latency) ----
        // vf[nd][s] = V^T[d = nd*32 + lq][key = k0 + 16s + 8hi + j]
        bf16x8 vf[2][2];
#pragma unroll
        for (int nd = 0; nd < 2; ++nd) {
            const uint16_t* vrow = vbase + (long)nd * 32 * 2048 + k0 + 8 * hi;
            vf[nd][0] = *(const bf16x8*)(vrow);
            vf[nd][1] = *(const bf16x8*)(vrow + 16);
        }

        // ---- scale (+ causal mask on boundary tiles) ----
        float sc[16];
        if (k0 + 31 > q0) {
            const int tq = q - (k0 + 4 * hi);    // mask iff keyconst > tq
#pragma unroll
            for (int r = 0; r < 16; ++r) {
                const int kc = (r & 3) + 8 * (r >> 2);
                sc[r] = st[r] * SCALE_LOG2 + (kc > tq ? NEG_BIG : 0.f);
            }
        } else {
#pragma unroll
            for (int r = 0; r < 16; ++r) sc[r] = st[r] * SCALE_LOG2;
        }

        // ---- in-register online softmax (one q-row per lane-pair) ----
        float vm = sc[0];
#pragma unroll
        for (int r = 1; r < 16; ++r) vm = fmaxf(vm, sc[r]);
        vm = fmaxf(vm, __shfl_xor(vm, 32));
        const float mnew = fmaxf(m_run, vm);
        const float alpha = __builtin_amdgcn_exp2f(m_run - mnew);
        m_run = mnew;

        float pr[16];
        float sum = 0.f;
#pragma unroll
        for (int r = 0; r < 16; ++r) {
            pr[r] = __builtin_amdgcn_exp2f(sc[r] - mnew);
            sum += pr[r];
        }
        sum += __shfl_xor(sum, 32);
        l_run = l_run * alpha + sum;

        // ---- pack P -> bf16 words, exchange halves, build P^T B-frags ----
        uint32_t wds[8], xw[8];
#pragma unroll
        for (int m = 0; m < 8; ++m)
            wds[m] = (uint32_t)f2bf(pr[2 * m]) | ((uint32_t)f2bf(pr[2 * m + 1]) << 16);
#pragma unroll
        for (int m = 0; m < 8; ++m)
            xw[m] = (uint32_t)__shfl_xor((int)wds[m], 32);

        bf16x8 pf[2];
#pragma unroll
        for (int s = 0; s < 2; ++s) {
            u32x4 pk;
            pk[0] = hi ? xw[4 * s + 2] : wds[4 * s + 0];
            pk[1] = hi ? xw[4 * s + 3] : wds[4 * s + 1];
            pk[2] = hi ? wds[4 * s + 2] : xw[4 * s + 0];
            pk[3] = hi ? wds[4 * s + 3] : xw[4 * s + 1];
            pf[s] = __builtin_bit_cast(bf16x8, pk);
        }

        // ---- rescale O, then PV accumulate ----
#pragma unroll
        for (int nd = 0; nd < 2; ++nd)
#pragma unroll
            for (int r = 0; r < 16; ++r) accO[nd][r] *= alpha;
#pragma unroll
        for (int nd = 0; nd < 2; ++nd)
#pragma unroll
            for (int s = 0; s < 2; ++s)
                accO[nd] = __builtin_amdgcn_mfma_f32_32x32x16_bf16(vf[nd][s], pf[s], accO[nd], 0, 0, 0);
    }

    // ---- epilogue: out[b, q, h*64 + d], d = nd*32 + (r&3)+4hi+8(r>>2) ----
    const float invl = 1.0f / l_run;
    uint16_t* orow = outb + (long)(b * 2048 + q) * 2048 + h * 64 + 4 * hi;
#pragma unroll
    for (int nd = 0; nd < 2; ++nd)
#pragma unroll
        for (int m = 0; m < 4; ++m) {
            ushort4 o;
            o.x = f2bf(accO[nd][4 * m + 0] * invl);
            o.y = f2bf(accO[nd][4 * m + 1] * invl);
            o.z = f2bf(accO[nd][4 * m + 2] * invl);
            o.w = f2bf(accO[nd][4 * m + 3] * invl);
            *(ushort4*)(orow + nd * 32 + 8 * m) = o;
        }
}

// ---------------------------------------------------------------------------
extern "C" void kernel_launch(void* const* d_in, const int* in_sizes, int n_in,
                              void* d_out, int out_size, void* d_ws, size_t ws_size,
                              hipStream_t stream) {
    const float* x    = (const float*)d_in[0];
    const float* wq   = (const float*)d_in[1];
    const float* wk   = (const float*)d_in[2];
    const float* wv   = (const float*)d_in[3];
    const float* wo   = (const float*)d_in[4];
    const float* fcos = (const float*)d_in[5];
    const float* fsin = (const float*)d_in[6];
    // d_in[7] = mask: causal, computed analytically in attn_fwd.
    float* out = (float*)d_out;

    uint8_t* ws = (uint8_t*)d_ws;
    // layout (bytes), total 52 MB:
    //   [0,        16777216)  x_bf [4096][2048]        -- reused as att_bf
    //   [16777216, 29360128)  w_bf [3072][2048]        -- reused: wo_bf (8MB) + Vt (4MB)
    //   [29360128, 54525952)  qkv_bf [4096][3072]
    uint16_t* x_bf   = (uint16_t*)(ws);
    uint16_t* w_bf   = (uint16_t*)(ws + 16777216);
    uint16_t* qkv_bf = (uint16_t*)(ws + 29360128);
    uint16_t* att_bf = x_bf;                            // alias after GEMM1
    uint16_t* wo_bf  = w_bf;                            // alias after GEMM1
    uint16_t* Vt     = (uint16_t*)(ws + 16777216 + 8388608);  // alias after GEMM1

    // 1) casts
    cvt4<<<(2097152 + 255) / 256, 256, 0, stream>>>(x, x_bf, 2097152);
    build_wqkv<<<(1572864 + 255) / 256, 256, 0, stream>>>(wq, wk, wv, w_bf);

    // 2) QKV projection: [4096][3072] = x_bf @ w_bf^T
    gemm_bt<1><<<dim3(32, 24), 256, 0, stream>>>(x_bf, w_bf, qkv_bf, 4096, 3072, 2048);

    // 3) RoPE on q,k columns
    rope_inplace<<<(4096 * 1280 + 255) / 256, 256, 0, stream>>>(qkv_bf, fcos, fsin);

    // 4) pack V^T (w_bf weights dead now), wo cast
    pack_vt<<<1024, 256, 0, stream>>>(qkv_bf, Vt);
    cvt4<<<(1048576 + 255) / 256, 256, 0, stream>>>(wo, wo_bf, 1048576);

    // 5) flash attention -> att_bf [4096][2048]
    attn_fwd<<<1024, 256, 0, stream>>>(qkv_bf, Vt, att_bf);

    // 6) O projection -> fp32 out
    gemm_bt<0><<<dim3(32, 16), 256, 0, stream>>>(att_bf, wo_bf, out, 4096, 2048, 2048);
}

// Round 5
// 236.730 us; speedup vs baseline: 2.2241x; 1.1898x over previous
//
#include <hip/hip_runtime.h>
#include <hip/hip_bf16.h>
#include <stdint.h>

// ---------------------------------------------------------------------------
// Attention layer: x->QKV proj -> RoPE -> causal GQA flash attn -> O proj
// B=2 S=2048 D=2048 H=32 KVH=8 HD=64. GEMMs bf16 MFMA 16x16x32; attention
// uses 32x32x16 swapped-operand QK^T (in-register softmax, zero LDS) with
// K/V pre-packed into per-lane fragment order (coalesced 1KB loads).
// ---------------------------------------------------------------------------

#define NEG_BIG (-1e9f)
#define SCALE_LOG2 0.18033688011112042f   // (1/sqrt(64)) * log2(e)

typedef __bf16 bf16x8 __attribute__((ext_vector_type(8)));
typedef float f32x4 __attribute__((ext_vector_type(4)));
typedef float f32x16 __attribute__((ext_vector_type(16)));
typedef uint16_t u16x8 __attribute__((ext_vector_type(8)));
typedef uint32_t u32x4 __attribute__((ext_vector_type(4)));

__device__ inline uint16_t f2bf(float x) {
    __hip_bfloat16 h = __float2bfloat16(x);
    return __builtin_bit_cast(uint16_t, h);
}
__device__ inline float bf2f(uint16_t u) {
    uint32_t t = (uint32_t)u << 16;
    return __builtin_bit_cast(float, t);
}

__device__ inline void async_cp16(const void* g, void* l) {
    __builtin_amdgcn_global_load_lds(
        (const __attribute__((address_space(1))) uint32_t*)g,
        (__attribute__((address_space(3))) uint32_t*)l,
        16 /*bytes*/, 0 /*offset*/, 0 /*aux*/);
}

// ------------------------- fp32 -> bf16 cast (4/thread) ---------------------
__global__ void cvt4(const float* __restrict__ in, uint16_t* __restrict__ out, int n4) {
    int i = blockIdx.x * blockDim.x + threadIdx.x;
    if (i >= n4) return;
    const float4 v = ((const float4*)in)[i];
    ushort4 o;
    o.x = f2bf(v.x); o.y = f2bf(v.y); o.z = f2bf(v.z); o.w = f2bf(v.w);
    ((ushort4*)out)[i] = o;
}

// ------------------- build concat W = [wq; wk; wv] in bf16 ------------------
__global__ void build_wqkv(const float* __restrict__ wq, const float* __restrict__ wk,
                           const float* __restrict__ wv, uint16_t* __restrict__ out) {
    int i = blockIdx.x * blockDim.x + threadIdx.x;   // one per 4 elements
    if (i >= (3072 * 2048) / 4) return;
    int e = i * 4;
    int row = e >> 11;           // /2048
    int col = e & 2047;
    const float* src = (row < 2048) ? (wq + (long)row * 2048 + col)
                     : (row < 2560) ? (wk + (long)(row - 2048) * 2048 + col)
                                    : (wv + (long)(row - 2560) * 2048 + col);
    const float4 v = *(const float4*)src;
    ushort4 o;
    o.x = f2bf(v.x); o.y = f2bf(v.y); o.z = f2bf(v.z); o.w = f2bf(v.w);
    ((ushort4*)(out + e))[0] = o;
}

// ------------------------------- GEMM (NT) ----------------------------------
// C[m][n] = sum_k A[m][k] * B[n][k];  A:[M][K] bf16, B:[N][K] bf16.
// 128x128 tile, BK=32, 256 threads (4 waves, 2x2), global_load_lds staging.
template <int OUT_BF16>
__global__ __launch_bounds__(256) void gemm_bt(const uint16_t* __restrict__ A,
                                               const uint16_t* __restrict__ Bw,
                                               void* __restrict__ Cout,
                                               int M, int N, int K) {
    __shared__ __align__(16) uint16_t Asm[128 * 32];
    __shared__ __align__(16) uint16_t Bsm[128 * 32];
    const int t = threadIdx.x;
    const int l = t & 63;
    const int w = t >> 6;
    const int wr = w >> 1, wc = w & 1;
    const int c = l & 15, g = l >> 4;
    const long row0 = (long)blockIdx.x * 128;
    const long col0 = (long)blockIdx.y * 128;

    f32x4 acc[4][4] = {};

    const uint16_t* aSrc = A + (row0 + (t >> 2)) * (long)K + (t & 3) * 8;
    const uint16_t* bSrc = Bw + (col0 + (t >> 2)) * (long)K + (t & 3) * 8;
    const long half = 64L * K;

    for (int k0 = 0; k0 < K; k0 += 32) {
        __syncthreads();                       // previous-iter LDS reads done
        async_cp16(aSrc + k0, &Asm[t * 8]);
        async_cp16(aSrc + half + k0, &Asm[2048 + t * 8]);
        async_cp16(bSrc + k0, &Bsm[t * 8]);
        async_cp16(bSrc + half + k0, &Bsm[2048 + t * 8]);
        __syncthreads();                       // staging complete (vmcnt drained)

        bf16x8 aF[4], bF[4];
        const int ko = g * 8;
#pragma unroll
        for (int m = 0; m < 4; ++m)
            aF[m] = *(const bf16x8*)&Asm[(wr * 64 + m * 16 + c) * 32 + ko];
#pragma unroll
        for (int n = 0; n < 4; ++n)
            bF[n] = *(const bf16x8*)&Bsm[(wc * 64 + n * 16 + c) * 32 + ko];
#pragma unroll
        for (int m = 0; m < 4; ++m)
#pragma unroll
            for (int n = 0; n < 4; ++n)
                acc[m][n] = __builtin_amdgcn_mfma_f32_16x16x32_bf16(aF[m], bF[n], acc[m][n], 0, 0, 0);
    }

#pragma unroll
    for (int m = 0; m < 4; ++m) {
        const long rg = row0 + wr * 64 + m * 16 + g * 4;
#pragma unroll
        for (int n = 0; n < 4; ++n) {
            const long cg = col0 + wc * 64 + n * 16 + c;
#pragma unroll
            for (int r = 0; r < 4; ++r) {
                float v = acc[m][n][r];
                if (OUT_BF16)
                    ((uint16_t*)Cout)[(rg + r) * (long)N + cg] = f2bf(v);
                else
                    ((float*)Cout)[(rg + r) * (long)N + cg] = v;
            }
        }
    }
}

// ------------------------------ RoPE in-place -------------------------------
__global__ void rope_inplace(uint16_t* __restrict__ qkv,
                             const float* __restrict__ cosT,
                             const float* __restrict__ sinT) {
    const int PPR = 1280;  // pairs per row: 1024 q + 256 k
    int idx = blockIdx.x * blockDim.x + threadIdx.x;
    if (idx >= 4096 * PPR) return;
    int m = idx / PPR;
    int j = idx - m * PPR;
    int col = (j < 1024) ? (2 * j) : (2048 + 2 * (j - 1024));
    int s = m & 2047;
    int d2 = j & 31;
    float cc = cosT[s * 32 + d2];
    float ss = sinT[s * 32 + d2];
    uint32_t* p = (uint32_t*)(qkv + (long)m * 3072 + col);
    uint32_t v = *p;
    float re = bf2f((uint16_t)(v & 0xffffu));
    float im = bf2f((uint16_t)(v >> 16));
    float orr = re * cc - im * ss;
    float oi = re * ss + im * cc;
    *p = (uint32_t)f2bf(orr) | ((uint32_t)f2bf(oi) << 16);
}

// --------------------------- V transpose pack -------------------------------
// Vt[bk][d(64)][s(2048)] <- qkv[:, 2560 + kvh*64 + d], bk = b*8+kvh.
__global__ void pack_vt(const uint16_t* __restrict__ qkv, uint16_t* __restrict__ Vt) {
    const int wid = (blockIdx.x * blockDim.x + threadIdx.x) >> 6;
    const int lane = threadIdx.x & 63;
    const int head = wid >> 8;          // bk, 0..15
    const int sblk = wid & 255;         // 8-row s block
    const int b = head >> 3, kvh = head & 7;
    const uint16_t* src = qkv + ((long)(b * 2048 + sblk * 8)) * 3072 + 2560 + kvh * 64 + lane;
    u16x8 v;
#pragma unroll
    for (int j = 0; j < 8; ++j) v[j] = src[(long)j * 3072];
    uint16_t* dst = Vt + ((long)head * 64 + lane) * 2048 + sblk * 8;
    *(u16x8*)dst = v;
}

// --------------------- K -> fragment-order pack ------------------------------
// Kpk[bk][tile(64)][s(4)][lane(64)][8]: lane l=(lq,hi) gets
// K[key=32*tile+lq][d=16s+8hi+j] (post-RoPE). Write fully coalesced.
__global__ void kpack(const uint16_t* __restrict__ qkv, uint16_t* __restrict__ Kpk) {
    const int wid = (blockIdx.x * blockDim.x + threadIdx.x) >> 6;  // 4096 waves
    const int l = threadIdx.x & 63;
    const int lq = l & 31, hi = l >> 5;
    const int s = wid & 3;
    const int tile = (wid >> 2) & 63;
    const int bk = wid >> 8;
    const int b = bk >> 3, kvh = bk & 7;
    const uint16_t* src = qkv + (long)(b * 2048 + 32 * tile + lq) * 3072
                        + 2048 + kvh * 64 + 16 * s + 8 * hi;
    u16x8 v = *(const u16x8*)src;
    *(u16x8*)(Kpk + (((long)(bk * 64 + tile) * 4 + s) * 64 + l) * 8) = v;
}

// --------------------- V^T -> fragment-order pack ----------------------------
// Vpk[bk][tile(64)][nd(2)][s2(2)][lane(64)][8]: lane l=(lq,hi) gets
// V^T[d=nd*32+lq][key=32*tile+16*s2+8*hi+j], read from Vt (16B vector loads).
__global__ void vpack2(const uint16_t* __restrict__ Vt, uint16_t* __restrict__ Vpk) {
    const int wid = (blockIdx.x * blockDim.x + threadIdx.x) >> 6;  // 4096 waves
    const int l = threadIdx.x & 63;
    const int lq = l & 31, hi = l >> 5;
    const int s2 = wid & 1;
    const int nd = (wid >> 1) & 1;
    const int tile = (wid >> 2) & 63;
    const int bk = wid >> 8;
    const uint16_t* src = Vt + ((long)(bk * 64 + nd * 32 + lq)) * 2048
                        + 32 * tile + 16 * s2 + 8 * hi;
    u16x8 v = *(const u16x8*)src;
    *(u16x8*)(Vpk + ((((long)(bk * 64 + tile) * 2 + nd) * 2 + s2) * 64 + l) * 8) = v;
}

// ---------------------------- flash attention -------------------------------
// 2048 blocks x 128 threads (2 waves). Block = (rowset j, head-pair bhp):
// both waves run the SAME rowset index j (rows 32j..32j+31) for heads
// gh = 2*bhp + ww -> identical duration (j+1 32-key tiles) => zero intra-block
// idle. Dispatch j descending (longest first) so scheduler backfill absorbs
// the causal work skew. Per lane-pair (l, l+32) one q-row fully in-register:
// swapped QK^T (S^T = mfma(K,Q)), in-register online softmax, P^T assembled
// via pack+shfl_xor(32); PV: O^T = mfma(V^T, P^T). K/V fragments come from
// Kpk/Vpk in per-lane order: every load = contiguous coalesced 1KB/wave.
__global__ __launch_bounds__(128, 4) void attn_fwd(const uint16_t* __restrict__ qkv,
                                                   const uint16_t* __restrict__ Kpk,
                                                   const uint16_t* __restrict__ Vpk,
                                                   uint16_t* __restrict__ outb) {
    const int bid = blockIdx.x;
    const int bhp = bid & 31;
    const int j = 63 - (bid >> 5);              // rowset index, longest first
    const int t = threadIdx.x;
    const int l = t & 63, ww = t >> 6;
    const int gh = 2 * bhp + ww;                // global head 0..63
    const int b = gh >> 5, h = gh & 31;
    const int kvh = h >> 2;
    const int bk = b * 8 + kvh;
    const int lq = l & 31, hi = l >> 5;
    const int q = 32 * j + lq;

    // Q B-fragments: qf[s] holds Q[q][d = 16s + 8*hi + jj], jj=0..7
    const uint16_t* qrow = qkv + (long)(b * 2048 + q) * 3072 + h * 64 + 8 * hi;
    bf16x8 qf[4];
#pragma unroll
    for (int s = 0; s < 4; ++s) qf[s] = *(const bf16x8*)(qrow + 16 * s);

    float m_run = -1e30f, l_run = 0.f;
    f32x16 accO[2] = {};                         // O^T[d = nd*32 + roff][q]

    const uint16_t* kbase = Kpk + (long)bk * 64 * 2048 + (long)l * 8;   // +tile*2048+s*512
    const uint16_t* vbase = Vpk + (long)bk * 64 * 2048 + (long)l * 8;   // +tile*2048+nd*1024+s2*512
    const int ntiles = j + 1;                    // 32-key tiles

    for (int tile = 0; tile < ntiles; ++tile) {
        // ---- K A-fragments (coalesced from Kpk) ----
        const uint16_t* kp = kbase + (long)tile * 2048;
        bf16x8 kf[4];
#pragma unroll
        for (int s = 0; s < 4; ++s) kf[s] = *(const bf16x8*)(kp + s * 512);

        // ---- S^T = K Q^T (lane: q = lq, key = k0 + (r&3)+4hi+8(r>>2)) ----
        f32x16 st = {};
#pragma unroll
        for (int s = 0; s < 4; ++s)
            st = __builtin_amdgcn_mfma_f32_32x32x16_bf16(kf[s], qf[s], st, 0, 0, 0);

        // ---- V^T A-fragments (issue early; softmax hides latency) ----
        const uint16_t* vp = vbase + (long)tile * 2048;
        bf16x8 vf[2][2];
#pragma unroll
        for (int nd = 0; nd < 2; ++nd)
#pragma unroll
            for (int s2 = 0; s2 < 2; ++s2)
                vf[nd][s2] = *(const bf16x8*)(vp + nd * 1024 + s2 * 512);

        // ---- scale (+ causal mask on the diagonal tile only) ----
        float sc[16];
        if (tile == j) {
            const int tq = lq - 4 * hi;          // mask iff keyconst > tq
#pragma unroll
            for (int r = 0; r < 16; ++r) {
                const int kc = (r & 3) + 8 * (r >> 2);
                sc[r] = st[r] * SCALE_LOG2 + (kc > tq ? NEG_BIG : 0.f);
            }
        } else {
#pragma unroll
            for (int r = 0; r < 16; ++r) sc[r] = st[r] * SCALE_LOG2;
        }

        // ---- in-register online softmax (one q-row per lane-pair) ----
        float vm = sc[0];
#pragma unroll
        for (int r = 1; r < 16; ++r) vm = fmaxf(vm, sc[r]);
        vm = fmaxf(vm, __shfl_xor(vm, 32));
        const float mnew = fmaxf(m_run, vm);
        const float alpha = __builtin_amdgcn_exp2f(m_run - mnew);
        m_run = mnew;

        float pr[16];
        float sum = 0.f;
#pragma unroll
        for (int r = 0; r < 16; ++r) {
            pr[r] = __builtin_amdgcn_exp2f(sc[r] - mnew);
            sum += pr[r];
        }
        sum += __shfl_xor(sum, 32);
        l_run = l_run * alpha + sum;

        // ---- pack P -> bf16 words, exchange halves, build P^T B-frags ----
        uint32_t wds[8], xw[8];
#pragma unroll
        for (int m = 0; m < 8; ++m)
            wds[m] = (uint32_t)f2bf(pr[2 * m]) | ((uint32_t)f2bf(pr[2 * m + 1]) << 16);
#pragma unroll
        for (int m = 0; m < 8; ++m)
            xw[m] = (uint32_t)__shfl_xor((int)wds[m], 32);

        bf16x8 pf[2];
#pragma unroll
        for (int s = 0; s < 2; ++s) {
            u32x4 pk;
            pk[0] = hi ? xw[4 * s + 2] : wds[4 * s + 0];
            pk[1] = hi ? xw[4 * s + 3] : wds[4 * s + 1];
            pk[2] = hi ? wds[4 * s + 2] : xw[4 * s + 0];
            pk[3] = hi ? wds[4 * s + 3] : xw[4 * s + 1];
            pf[s] = __builtin_bit_cast(bf16x8, pk);
        }

        // ---- rescale O, then PV accumulate ----
#pragma unroll
        for (int nd = 0; nd < 2; ++nd)
#pragma unroll
            for (int r = 0; r < 16; ++r) accO[nd][r] *= alpha;
#pragma unroll
        for (int nd = 0; nd < 2; ++nd)
#pragma unroll
            for (int s = 0; s < 2; ++s)
                accO[nd] = __builtin_amdgcn_mfma_f32_32x32x16_bf16(vf[nd][s], pf[s], accO[nd], 0, 0, 0);
    }

    // ---- epilogue: out[b, q, h*64 + d], d = nd*32 + (r&3)+4hi+8(r>>2) ----
    const float invl = 1.0f / l_run;
    uint16_t* orow = outb + (long)(b * 2048 + q) * 2048 + h * 64 + 4 * hi;
#pragma unroll
    for (int nd = 0; nd < 2; ++nd)
#pragma unroll
        for (int m = 0; m < 4; ++m) {
            ushort4 o;
            o.x = f2bf(accO[nd][4 * m + 0] * invl);
            o.y = f2bf(accO[nd][4 * m + 1] * invl);
            o.z = f2bf(accO[nd][4 * m + 2] * invl);
            o.w = f2bf(accO[nd][4 * m + 3] * invl);
            *(ushort4*)(orow + nd * 32 + 8 * m) = o;
        }
}

// ---------------------------------------------------------------------------
extern "C" void kernel_launch(void* const* d_in, const int* in_sizes, int n_in,
                              void* d_out, int out_size, void* d_ws, size_t ws_size,
                              hipStream_t stream) {
    const float* x    = (const float*)d_in[0];
    const float* wq   = (const float*)d_in[1];
    const float* wk   = (const float*)d_in[2];
    const float* wv   = (const float*)d_in[3];
    const float* wo   = (const float*)d_in[4];
    const float* fcos = (const float*)d_in[5];
    const float* fsin = (const float*)d_in[6];
    // d_in[7] = mask: causal, computed analytically in attn_fwd.
    float* out = (float*)d_out;

    uint8_t* ws = (uint8_t*)d_ws;
    // layout (bytes), total 52 MiB:
    //   [0,        16 MiB)   x_bf [4096][2048]   -- reused as att_bf
    //   [16 MiB,   28 MiB)   w_bf [3072][2048]   -- after GEMM1:
    //                          Kpk @16MiB (4MiB), Vpk @20MiB (4MiB), Vt @24MiB (4MiB)
    //                          after attn: wo_bf @16MiB (8MiB)
    //   [28 MiB,   52 MiB)   qkv_bf [4096][3072]
    const size_t MiB = 1048576;
    uint16_t* x_bf   = (uint16_t*)(ws);
    uint16_t* w_bf   = (uint16_t*)(ws + 16 * MiB);
    uint16_t* qkv_bf = (uint16_t*)(ws + 28 * MiB);
    uint16_t* att_bf = x_bf;                        // alias after GEMM1
    uint16_t* Kpk    = (uint16_t*)(ws + 16 * MiB);  // alias after GEMM1
    uint16_t* Vpk    = (uint16_t*)(ws + 20 * MiB);
    uint16_t* Vt     = (uint16_t*)(ws + 24 * MiB);
    uint16_t* wo_bf  = (uint16_t*)(ws + 16 * MiB);  // alias after attn

    // 1) casts
    cvt4<<<(2097152 + 255) / 256, 256, 0, stream>>>(x, x_bf, 2097152);
    build_wqkv<<<(1572864 + 255) / 256, 256, 0, stream>>>(wq, wk, wv, w_bf);

    // 2) QKV projection: [4096][3072] = x_bf @ w_bf^T
    gemm_bt<1><<<dim3(32, 24), 256, 0, stream>>>(x_bf, w_bf, qkv_bf, 4096, 3072, 2048);

    // 3) RoPE on q,k columns
    rope_inplace<<<(4096 * 1280 + 255) / 256, 256, 0, stream>>>(qkv_bf, fcos, fsin);

    // 4) fragment-order packs (weights dead after GEMM1)
    pack_vt<<<1024, 256, 0, stream>>>(qkv_bf, Vt);
    kpack<<<1024, 256, 0, stream>>>(qkv_bf, Kpk);
    vpack2<<<1024, 256, 0, stream>>>(Vt, Vpk);

    // 5) flash attention -> att_bf [4096][2048]
    attn_fwd<<<2048, 128, 0, stream>>>(qkv_bf, Kpk, Vpk, att_bf);

    // 6) wo cast (Kpk/Vpk dead now), O projection -> fp32 out
    cvt4<<<(1048576 + 255) / 256, 256, 0, stream>>>(wo, wo_bf, 1048576);
    gemm_bt<0><<<dim3(32, 16), 256, 0, stream>>>(att_bf, wo_bf, out, 4096, 2048, 2048);
}

// Round 6
// 230.565 us; speedup vs baseline: 2.2835x; 1.0267x over previous
//
#include <hip/hip_runtime.h>
#include <hip/hip_bf16.h>
#include <stdint.h>

// ---------------------------------------------------------------------------
// Attention layer: x->QKV proj -> RoPE -> causal GQA flash attn -> O proj
// B=2 S=2048 D=2048 H=32 KVH=8 HD=64. GEMMs bf16 MFMA 16x16x32; attention
// uses 32x32x16 swapped-operand QK^T (in-register softmax, zero LDS) with
// K/V pre-packed into per-lane fragment order. 64-key iterations with
// defer-max (T13) and setprio (T5).
// ---------------------------------------------------------------------------

#define NEG_BIG (-1e9f)
#define SCALE_LOG2 0.18033688011112042f   // (1/sqrt(64)) * log2(e)
#define DEFER_THR 10.0f                   // log2-domain defer-max threshold

typedef __bf16 bf16x8 __attribute__((ext_vector_type(8)));
typedef float f32x4 __attribute__((ext_vector_type(4)));
typedef float f32x16 __attribute__((ext_vector_type(16)));
typedef uint16_t u16x8 __attribute__((ext_vector_type(8)));
typedef uint32_t u32x4 __attribute__((ext_vector_type(4)));

__device__ inline uint16_t f2bf(float x) {
    __hip_bfloat16 h = __float2bfloat16(x);
    return __builtin_bit_cast(uint16_t, h);
}
__device__ inline float bf2f(uint16_t u) {
    uint32_t t = (uint32_t)u << 16;
    return __builtin_bit_cast(float, t);
}

__device__ inline void async_cp16(const void* g, void* l) {
    __builtin_amdgcn_global_load_lds(
        (const __attribute__((address_space(1))) uint32_t*)g,
        (__attribute__((address_space(3))) uint32_t*)l,
        16 /*bytes*/, 0 /*offset*/, 0 /*aux*/);
}

// ------------------------- fp32 -> bf16 cast (4/thread) ---------------------
__global__ void cvt4(const float* __restrict__ in, uint16_t* __restrict__ out, int n4) {
    int i = blockIdx.x * blockDim.x + threadIdx.x;
    if (i >= n4) return;
    const float4 v = ((const float4*)in)[i];
    ushort4 o;
    o.x = f2bf(v.x); o.y = f2bf(v.y); o.z = f2bf(v.z); o.w = f2bf(v.w);
    ((ushort4*)out)[i] = o;
}

// ------------------- build concat W = [wq; wk; wv] in bf16 ------------------
__global__ void build_wqkv(const float* __restrict__ wq, const float* __restrict__ wk,
                           const float* __restrict__ wv, uint16_t* __restrict__ out) {
    int i = blockIdx.x * blockDim.x + threadIdx.x;   // one per 4 elements
    if (i >= (3072 * 2048) / 4) return;
    int e = i * 4;
    int row = e >> 11;           // /2048
    int col = e & 2047;
    const float* src = (row < 2048) ? (wq + (long)row * 2048 + col)
                     : (row < 2560) ? (wk + (long)(row - 2048) * 2048 + col)
                                    : (wv + (long)(row - 2560) * 2048 + col);
    const float4 v = *(const float4*)src;
    ushort4 o;
    o.x = f2bf(v.x); o.y = f2bf(v.y); o.z = f2bf(v.z); o.w = f2bf(v.w);
    ((ushort4*)(out + e))[0] = o;
}

// ------------------------------- GEMM (NT) ----------------------------------
// C[m][n] = sum_k A[m][k] * B[n][k];  A:[M][K] bf16, B:[N][K] bf16.
// 128x128 tile, BK=32, 256 threads (4 waves, 2x2), global_load_lds staging.
template <int OUT_BF16>
__global__ __launch_bounds__(256) void gemm_bt(const uint16_t* __restrict__ A,
                                               const uint16_t* __restrict__ Bw,
                                               void* __restrict__ Cout,
                                               int M, int N, int K) {
    __shared__ __align__(16) uint16_t Asm[128 * 32];
    __shared__ __align__(16) uint16_t Bsm[128 * 32];
    const int t = threadIdx.x;
    const int l = t & 63;
    const int w = t >> 6;
    const int wr = w >> 1, wc = w & 1;
    const int c = l & 15, g = l >> 4;
    const long row0 = (long)blockIdx.x * 128;
    const long col0 = (long)blockIdx.y * 128;

    f32x4 acc[4][4] = {};

    const uint16_t* aSrc = A + (row0 + (t >> 2)) * (long)K + (t & 3) * 8;
    const uint16_t* bSrc = Bw + (col0 + (t >> 2)) * (long)K + (t & 3) * 8;
    const long half = 64L * K;

    for (int k0 = 0; k0 < K; k0 += 32) {
        __syncthreads();                       // previous-iter LDS reads done
        async_cp16(aSrc + k0, &Asm[t * 8]);
        async_cp16(aSrc + half + k0, &Asm[2048 + t * 8]);
        async_cp16(bSrc + k0, &Bsm[t * 8]);
        async_cp16(bSrc + half + k0, &Bsm[2048 + t * 8]);
        __syncthreads();                       // staging complete (vmcnt drained)

        bf16x8 aF[4], bF[4];
        const int ko = g * 8;
#pragma unroll
        for (int m = 0; m < 4; ++m)
            aF[m] = *(const bf16x8*)&Asm[(wr * 64 + m * 16 + c) * 32 + ko];
#pragma unroll
        for (int n = 0; n < 4; ++n)
            bF[n] = *(const bf16x8*)&Bsm[(wc * 64 + n * 16 + c) * 32 + ko];
#pragma unroll
        for (int m = 0; m < 4; ++m)
#pragma unroll
            for (int n = 0; n < 4; ++n)
                acc[m][n] = __builtin_amdgcn_mfma_f32_16x16x32_bf16(aF[m], bF[n], acc[m][n], 0, 0, 0);
    }

#pragma unroll
    for (int m = 0; m < 4; ++m) {
        const long rg = row0 + wr * 64 + m * 16 + g * 4;
#pragma unroll
        for (int n = 0; n < 4; ++n) {
            const long cg = col0 + wc * 64 + n * 16 + c;
#pragma unroll
            for (int r = 0; r < 4; ++r) {
                float v = acc[m][n][r];
                if (OUT_BF16)
                    ((uint16_t*)Cout)[(rg + r) * (long)N + cg] = f2bf(v);
                else
                    ((float*)Cout)[(rg + r) * (long)N + cg] = v;
            }
        }
    }
}

// --------------------------- RoPE in-place (Q only) -------------------------
__global__ void rope_q(uint16_t* __restrict__ qkv,
                       const float* __restrict__ cosT,
                       const float* __restrict__ sinT) {
    int idx = blockIdx.x * blockDim.x + threadIdx.x;   // one per q pair
    if (idx >= 4096 * 1024) return;
    int m = idx >> 10;
    int j = idx & 1023;
    int s = m & 2047;
    int d2 = j & 31;
    float cc = cosT[s * 32 + d2];
    float ss = sinT[s * 32 + d2];
    uint32_t* p = (uint32_t*)(qkv + (long)m * 3072 + 2 * j);
    uint32_t v = *p;
    float re = bf2f((uint16_t)(v & 0xffffu));
    float im = bf2f((uint16_t)(v >> 16));
    float orr = re * cc - im * ss;
    float oi = re * ss + im * cc;
    *p = (uint32_t)f2bf(orr) | ((uint32_t)f2bf(oi) << 16);
}

// --------------- K -> fragment-order pack with fused RoPE --------------------
// Kpk[bk][tile(64)][s(4)][lane(64)][8]: lane l=(lq,hi) gets
// RoPE(K)[key=32*tile+lq][d=16s+8hi+jj]. Source K in qkv is pre-RoPE; the 8
// loaded elements form 4 complete rope pairs (d0 = 16s+8hi is even-aligned).
__global__ void kpack_rope(const uint16_t* __restrict__ qkv,
                           const float* __restrict__ cosT,
                           const float* __restrict__ sinT,
                           uint16_t* __restrict__ Kpk) {
    const int wid = (blockIdx.x * blockDim.x + threadIdx.x) >> 6;  // 4096 waves
    const int l = threadIdx.x & 63;
    const int lq = l & 31, hi = l >> 5;
    const int s = wid & 3;
    const int tile = (wid >> 2) & 63;
    const int bk = wid >> 8;
    const int b = bk >> 3, kvh = bk & 7;
    const int key = 32 * tile + lq;
    const uint16_t* src = qkv + (long)(b * 2048 + key) * 3072
                        + 2048 + kvh * 64 + 16 * s + 8 * hi;
    u16x8 v = *(const u16x8*)src;
    const int d2b = 8 * s + 4 * hi;            // first pair index
    u16x8 o;
#pragma unroll
    for (int p = 0; p < 4; ++p) {
        const float cc = cosT[key * 32 + d2b + p];
        const float ss = sinT[key * 32 + d2b + p];
        const float re = bf2f(v[2 * p]);
        const float im = bf2f(v[2 * p + 1]);
        o[2 * p]     = f2bf(re * cc - im * ss);
        o[2 * p + 1] = f2bf(re * ss + im * cc);
    }
    *(u16x8*)(Kpk + (((long)(bk * 64 + tile) * 4 + s) * 64 + l) * 8) = o;
}

// --------------- V^T -> fragment-order pack (direct from qkv) ----------------
// Vpk[bk][tile(64)][nd(2)][s2(2)][lane(64)][8]: lane l=(lq,hi) gets
// V^T[d=nd*32+lq][key=32*tile+16*s2+8*hi+jj]  (8 strided row reads).
__global__ void vpack_direct(const uint16_t* __restrict__ qkv, uint16_t* __restrict__ Vpk) {
    const int wid = (blockIdx.x * blockDim.x + threadIdx.x) >> 6;  // 4096 waves
    const int l = threadIdx.x & 63;
    const int lq = l & 31, hi = l >> 5;
    const int s2 = wid & 1;
    const int nd = (wid >> 1) & 1;
    const int tile = (wid >> 2) & 63;
    const int bk = wid >> 8;
    const int b = bk >> 3, kvh = bk & 7;
    const int key0 = 32 * tile + 16 * s2 + 8 * hi;
    const uint16_t* src = qkv + (long)(b * 2048 + key0) * 3072
                        + 2560 + kvh * 64 + nd * 32 + lq;
    u16x8 v;
#pragma unroll
    for (int jj = 0; jj < 8; ++jj) v[jj] = src[(long)jj * 3072];
    *(u16x8*)(Vpk + ((((long)(bk * 64 + tile) * 2 + nd) * 2 + s2) * 64 + l) * 8) = v;
}

// ------------------- P^T fragment assembly (verified R3/R4) ------------------
__device__ inline void pack_pf(const float pr[16], int hi, bf16x8 pf[2]) {
    uint32_t wds[8], xw[8];
#pragma unroll
    for (int m = 0; m < 8; ++m)
        wds[m] = (uint32_t)f2bf(pr[2 * m]) | ((uint32_t)f2bf(pr[2 * m + 1]) << 16);
#pragma unroll
    for (int m = 0; m < 8; ++m)
        xw[m] = (uint32_t)__shfl_xor((int)wds[m], 32);
#pragma unroll
    for (int s = 0; s < 2; ++s) {
        u32x4 pk;
        pk[0] = hi ? xw[4 * s + 2] : wds[4 * s + 0];
        pk[1] = hi ? xw[4 * s + 3] : wds[4 * s + 1];
        pk[2] = hi ? wds[4 * s + 2] : xw[4 * s + 0];
        pk[3] = hi ? wds[4 * s + 3] : xw[4 * s + 1];
        pf[s] = __builtin_bit_cast(bf16x8, pk);
    }
}

// ---------------------------- flash attention -------------------------------
// 2048 blocks x 128 threads (2 waves). Block = (rowset j, head-pair): both
// waves run the same j (rows 32j..32j+31) -> identical duration; j dispatched
// descending (LPT). Per lane-pair (l,l+32) one q-row in-register: swapped
// QK^T (S^T = mfma(K,Q)), in-register online softmax over 64-key chunks with
// defer-max, P^T via pack+shfl_xor(32), PV: O^T = mfma(V^T, P^T).
__global__ __launch_bounds__(128) void attn_fwd(const uint16_t* __restrict__ qkv,
                                                const uint16_t* __restrict__ Kpk,
                                                const uint16_t* __restrict__ Vpk,
                                                uint16_t* __restrict__ outb) {
    const int bid = blockIdx.x;
    const int bhp = bid & 31;
    const int j = 63 - (bid >> 5);              // rowset index, longest first
    const int t0 = threadIdx.x;
    const int l = t0 & 63, ww = t0 >> 6;
    const int gh = 2 * bhp + ww;                // global head 0..63
    const int b = gh >> 5, h = gh & 31;
    const int kvh = h >> 2;
    const int bk = b * 8 + kvh;
    const int lq = l & 31, hi = l >> 5;
    const int q = 32 * j + lq;

    // Q B-fragments: qf[s] holds Q[q][d = 16s + 8*hi + jj]
    const uint16_t* qrow = qkv + (long)(b * 2048 + q) * 3072 + h * 64 + 8 * hi;
    bf16x8 qf[4];
#pragma unroll
    for (int s = 0; s < 4; ++s) qf[s] = *(const bf16x8*)(qrow + 16 * s);

    float m_run = -1e30f, l_run = 0.f;
    f32x16 accO[2] = {};                         // O^T[d = nd*32 + roff][q]

    const uint16_t* kbase = Kpk + (long)bk * 64 * 2048 + (long)l * 8;
    const uint16_t* vbase = Vpk + (long)bk * 64 * 2048 + (long)l * 8;
    const int nT = (j + 2) >> 1;                 // 64-key iterations

    for (int t = 0; t < nT; ++t) {
        // ---- K A-fragments for both 32-key subtiles (coalesced) ----
        bf16x8 kf[2][4];
#pragma unroll
        for (int u = 0; u < 2; ++u)
#pragma unroll
            for (int s = 0; s < 4; ++s)
                kf[u][s] = *(const bf16x8*)(kbase + (long)(2 * t + u) * 2048 + s * 512);

        // ---- S^T = K Q^T ----
        f32x16 st0 = {}, st1 = {};
        __builtin_amdgcn_s_setprio(1);
#pragma unroll
        for (int s = 0; s < 4; ++s)
            st0 = __builtin_amdgcn_mfma_f32_32x32x16_bf16(kf[0][s], qf[s], st0, 0, 0, 0);
#pragma unroll
        for (int s = 0; s < 4; ++s)
            st1 = __builtin_amdgcn_mfma_f32_32x32x16_bf16(kf[1][s], qf[s], st1, 0, 0, 0);
        __builtin_amdgcn_s_setprio(0);

        // ---- V^T A-fragments (kf dead; softmax below hides latency) ----
        bf16x8 vf[2][2][2];
#pragma unroll
        for (int u = 0; u < 2; ++u)
#pragma unroll
            for (int nd = 0; nd < 2; ++nd)
#pragma unroll
                for (int s2 = 0; s2 < 2; ++s2)
                    vf[u][nd][s2] = *(const bf16x8*)(vbase + (long)(2 * t + u) * 2048 + nd * 1024 + s2 * 512);

        // ---- scale (+ causal mask on the last iteration only) ----
        float sc0[16], sc1[16];
        if (t == nT - 1) {
            const int tq0 = lq + ((j - 2 * t) << 5) - 4 * hi;
            const int tq1 = tq0 - 32;
#pragma unroll
            for (int r = 0; r < 16; ++r) {
                const int kc = (r & 3) + 8 * (r >> 2);
                sc0[r] = st0[r] * SCALE_LOG2 + (kc > tq0 ? NEG_BIG : 0.f);
                sc1[r] = st1[r] * SCALE_LOG2 + (kc > tq1 ? NEG_BIG : 0.f);
            }
        } else {
#pragma unroll
            for (int r = 0; r < 16; ++r) {
                sc0[r] = st0[r] * SCALE_LOG2;
                sc1[r] = st1[r] * SCALE_LOG2;
            }
        }

        // ---- 64-key max, defer-max rescale (T13) ----
        float vm = sc0[0];
#pragma unroll
        for (int r = 1; r < 16; ++r) vm = fmaxf(vm, sc0[r]);
#pragma unroll
        for (int r = 0; r < 16; ++r) vm = fmaxf(vm, sc1[r]);
        vm = fmaxf(vm, __shfl_xor(vm, 32));
        if (!__all(vm - m_run <= DEFER_THR)) {
            const float mnew = fmaxf(m_run, vm);
            const float alpha = __builtin_amdgcn_exp2f(m_run - mnew);
            m_run = mnew;
            l_run *= alpha;
#pragma unroll
            for (int nd = 0; nd < 2; ++nd)
#pragma unroll
                for (int r = 0; r < 16; ++r) accO[nd][r] *= alpha;
        }

        // ---- exp + row-sum ----
        float pr0[16], pr1[16];
        float sum = 0.f;
#pragma unroll
        for (int r = 0; r < 16; ++r) {
            pr0[r] = __builtin_amdgcn_exp2f(sc0[r] - m_run);
            sum += pr0[r];
        }
#pragma unroll
        for (int r = 0; r < 16; ++r) {
            pr1[r] = __builtin_amdgcn_exp2f(sc1[r] - m_run);
            sum += pr1[r];
        }
        sum += __shfl_xor(sum, 32);
        l_run += sum;

        // ---- P^T fragments, PV accumulate ----
        bf16x8 pf0[2], pf1[2];
        pack_pf(pr0, hi, pf0);
        pack_pf(pr1, hi, pf1);

        __builtin_amdgcn_s_setprio(1);
#pragma unroll
        for (int nd = 0; nd < 2; ++nd) {
            accO[nd] = __builtin_amdgcn_mfma_f32_32x32x16_bf16(vf[0][nd][0], pf0[0], accO[nd], 0, 0, 0);
            accO[nd] = __builtin_amdgcn_mfma_f32_32x32x16_bf16(vf[0][nd][1], pf0[1], accO[nd], 0, 0, 0);
            accO[nd] = __builtin_amdgcn_mfma_f32_32x32x16_bf16(vf[1][nd][0], pf1[0], accO[nd], 0, 0, 0);
            accO[nd] = __builtin_amdgcn_mfma_f32_32x32x16_bf16(vf[1][nd][1], pf1[1], accO[nd], 0, 0, 0);
        }
        __builtin_amdgcn_s_setprio(0);
    }

    // ---- epilogue: out[b, q, h*64 + d], d = nd*32 + (r&3)+4hi+8(r>>2) ----
    const float invl = 1.0f / l_run;
    uint16_t* orow = outb + (long)(b * 2048 + q) * 2048 + h * 64 + 4 * hi;
#pragma unroll
    for (int nd = 0; nd < 2; ++nd)
#pragma unroll
        for (int m = 0; m < 4; ++m) {
            ushort4 o;
            o.x = f2bf(accO[nd][4 * m + 0] * invl);
            o.y = f2bf(accO[nd][4 * m + 1] * invl);
            o.z = f2bf(accO[nd][4 * m + 2] * invl);
            o.w = f2bf(accO[nd][4 * m + 3] * invl);
            *(ushort4*)(orow + nd * 32 + 8 * m) = o;
        }
}

// ---------------------------------------------------------------------------
extern "C" void kernel_launch(void* const* d_in, const int* in_sizes, int n_in,
                              void* d_out, int out_size, void* d_ws, size_t ws_size,
                              hipStream_t stream) {
    const float* x    = (const float*)d_in[0];
    const float* wq   = (const float*)d_in[1];
    const float* wk   = (const float*)d_in[2];
    const float* wv   = (const float*)d_in[3];
    const float* wo   = (const float*)d_in[4];
    const float* fcos = (const float*)d_in[5];
    const float* fsin = (const float*)d_in[6];
    // d_in[7] = mask: causal, computed analytically in attn_fwd.
    float* out = (float*)d_out;

    uint8_t* ws = (uint8_t*)d_ws;
    // layout (bytes), total 52 MiB:
    //   [0,        16 MiB)   x_bf [4096][2048]   -- reused as att_bf
    //   [16 MiB,   28 MiB)   w_bf [3072][2048]   -- after GEMM1:
    //                          Kpk @16MiB (4MiB), Vpk @20MiB (4MiB)
    //                          after attn: wo_bf @16MiB (8MiB)
    //   [28 MiB,   52 MiB)   qkv_bf [4096][3072]
    const size_t MiB = 1048576;
    uint16_t* x_bf   = (uint16_t*)(ws);
    uint16_t* w_bf   = (uint16_t*)(ws + 16 * MiB);
    uint16_t* qkv_bf = (uint16_t*)(ws + 28 * MiB);
    uint16_t* att_bf = x_bf;                        // alias after GEMM1
    uint16_t* Kpk    = (uint16_t*)(ws + 16 * MiB);  // alias after GEMM1
    uint16_t* Vpk    = (uint16_t*)(ws + 20 * MiB);
    uint16_t* wo_bf  = (uint16_t*)(ws + 16 * MiB);  // alias after attn

    // 1) casts
    cvt4<<<(2097152 + 255) / 256, 256, 0, stream>>>(x, x_bf, 2097152);
    build_wqkv<<<(1572864 + 255) / 256, 256, 0, stream>>>(wq, wk, wv, w_bf);

    // 2) QKV projection: [4096][3072] = x_bf @ w_bf^T
    gemm_bt<1><<<dim3(32, 24), 256, 0, stream>>>(x_bf, w_bf, qkv_bf, 4096, 3072, 2048);

    // 3) RoPE on Q (K roped inside kpack_rope); fragment-order packs
    rope_q<<<16384, 256, 0, stream>>>(qkv_bf, fcos, fsin);
    kpack_rope<<<1024, 256, 0, stream>>>(qkv_bf, fcos, fsin, Kpk);
    vpack_direct<<<1024, 256, 0, stream>>>(qkv_bf, Vpk);

    // 4) flash attention -> att_bf [4096][2048]
    attn_fwd<<<2048, 128, 0, stream>>>(qkv_bf, Kpk, Vpk, att_bf);

    // 5) wo cast (Kpk/Vpk dead now), O projection -> fp32 out
    cvt4<<<(1048576 + 255) / 256, 256, 0, stream>>>(wo, wo_bf, 1048576);
    gemm_bt<0><<<dim3(32, 16), 256, 0, stream>>>(att_bf, wo_bf, out, 4096, 2048, 2048);
}